// Round 1
// baseline (4346.007 us; speedup 1.0000x reference)
//
#include <hip/hip_runtime.h>

#define NTIME 30
#define NB 4096

typedef __attribute__((ext_vector_type(8))) short short8;
typedef __attribute__((ext_vector_type(4))) float f32x4;
typedef __attribute__((ext_vector_type(16))) float f32x16;

__device__ __forceinline__ unsigned short f2b(float f) {
    unsigned int u = __float_as_uint(f);
    u = u + 0x7FFFu + ((u >> 16) & 1u);        // RNE to bf16
    return (unsigned short)(u >> 16);
}
__device__ __forceinline__ float b2f(unsigned short s) {
    return __uint_as_float(((unsigned int)s) << 16);
}
__device__ __forceinline__ float sigf(float x)     { return 1.0f / (1.0f + __expf(-x)); }
__device__ __forceinline__ float tanhfast(float x) { return 1.0f - 2.0f / (__expf(2.0f * x) + 1.0f); }

// LDS-only barrier: all cross-wave communication inside lstm3 is via LDS, so we
// only need lgkmcnt(0)+s_barrier. Crucially this does NOT drain vmcnt, letting
// global weight prefetches stay in flight across phase boundaries (__syncthreads
// emits s_waitcnt vmcnt(0) and kills the pipeline every phase).
__device__ __forceinline__ void bar_lds() {
    asm volatile("s_waitcnt lgkmcnt(0)" ::: "memory");
    __builtin_amdgcn_s_barrier();
    asm volatile("" ::: "memory");
}

// ---- L1 weight pack: 32x32x16 B-frags, bf16 hi/lo planes (layout unchanged, validated).
__global__ __launch_bounds__(256) void prep_w32(const float* __restrict__ Wih,
                                                const float* __restrict__ Whh,
                                                unsigned short* __restrict__ out)
{
    int e = blockIdx.x * 256 + threadIdx.x;
    if (e >= 36 * 65536) return;
    int j     = e & 7;
    int lane  = (e >> 3) & 63;
    int plane = (e >> 9) & 1;
    int g     = (e >> 10) & 3;
    int w     = (e >> 12) & 15;
    int s     = e >> 16;
    int n = lane & 31, kh = lane >> 5;
    int unit = w * 32 + n;
    int k = s * 16 + kh * 8 + j;
    int row = g * 512 + unit;
    float v = 0.0f;
    if (k < 64) { if (k < 58) v = Wih[row * 58 + k]; }
    else        { v = Whh[row * 512 + (k - 64)]; }
    unsigned short hi = f2b(v);
    out[e] = plane ? f2b(v - b2f(hi)) : hi;
}

// ---- L2/L3 weight pack: 16x16x32 B-frags (validated layout).
__global__ __launch_bounds__(256) void prep_w16(const float* __restrict__ Wih,
                                                const float* __restrict__ Whh,
                                                unsigned short* __restrict__ out,
                                                int H, int KI, int KIp, int KH, int CG, int KS)
{
    int e = blockIdx.x * 256 + threadIdx.x;
    if (e >= KS * CG * 4096) return;
    int j     = e & 7;
    int lane  = (e >> 3) & 63;
    int plane = (e >> 9) & 1;
    int g     = (e >> 10) & 3;
    int rest  = e >> 12;
    int cg = rest % CG;
    int s  = rest / CG;
    int n = lane & 15, q = lane >> 4;
    int unit = cg * 16 + n;
    int k = s * 32 + q * 8 + j;
    int row = g * H + unit;
    float v = 0.0f;
    if (k < KIp) { if (k < KI) v = Wih[row * KI + k]; }
    else         { v = Whh[row * KH + (k - KIp)]; }
    unsigned short hi = f2b(v);
    out[e] = plane ? f2b(v - b2f(hi)) : hi;
}

// ---- Head weight transposes (o-fastest float4 blocks)
__global__ __launch_bounds__(256) void pack_wt1(const float* __restrict__ Wf1, float4* __restrict__ WT1)
{
    int e = blockIdx.x * 256 + threadIdx.x;
    if (e >= 480 * 1024) return;
    int kc = e >> 10, o = e & 1023;
    float4 v = {0.0f, 0.0f, 0.0f, 0.0f};
    if (o < 960) {
        const float* p = Wf1 + (size_t)o * 1920 + kc * 4;
        v.x = p[0]; v.y = p[1]; v.z = p[2]; v.w = p[3];
    }
    WT1[e] = v;
}
__global__ __launch_bounds__(256) void pack_wt2(const float* __restrict__ Wf2, float4* __restrict__ WT2)
{
    int e = blockIdx.x * 256 + threadIdx.x;
    if (e >= 256 * 512) return;
    int kc = e >> 9, o = e & 511;
    float4 v = {0.0f, 0.0f, 0.0f, 0.0f};
    if (o < 480) {
        int k = kc * 4;
        v.x = (k + 0 < 960) ? Wf2[(size_t)o * 960 + k + 0] : 0.0f;
        v.y = (k + 1 < 960) ? Wf2[(size_t)o * 960 + k + 1] : 0.0f;
        v.z = (k + 2 < 960) ? Wf2[(size_t)o * 960 + k + 2] : 0.0f;
        v.w = (k + 3 < 960) ? Wf2[(size_t)o * 960 + k + 3] : 0.0f;
    }
    WT2[e] = v;
}

#define MFMA32(A, X, B) A = __builtin_amdgcn_mfma_f32_32x32x16_bf16((X), (B), (A), 0, 0, 0)
#define MFMA16(A, X, B) A = __builtin_amdgcn_mfma_f32_16x16x32_bf16((X), (B), (A), 0, 0, 0)

// weight fetch helpers: offsets within a k-step slab: (g,plane) -> g*1024 + plane*512
#define FETCH4(BB, Q0, Q1, Q2, Q3) do { \
    const unsigned short* _bb = (BB); \
    Q0 = *(const short8*)(_bb); \
    Q1 = *(const short8*)(_bb + 512); \
    Q2 = *(const short8*)(_bb + 1024); \
    Q3 = *(const short8*)(_bb + 1536); \
} while (0)

#define FETCH8(BB, Q0, Q1, Q2, Q3, Q4, Q5, Q6, Q7) do { \
    const unsigned short* _bb = (BB); \
    Q0 = *(const short8*)(_bb); \
    Q1 = *(const short8*)(_bb + 512); \
    Q2 = *(const short8*)(_bb + 1024); \
    Q3 = *(const short8*)(_bb + 1536); \
    Q4 = *(const short8*)(_bb + 2048); \
    Q5 = *(const short8*)(_bb + 2560); \
    Q6 = *(const short8*)(_bb + 3072); \
    Q7 = *(const short8*)(_bb + 3584); \
} while (0)

// L1 A-fragment load (x for s<4, h1 otherwise)
#define L1_LOAD_A(SV) do { \
    if ((SV) < 4) { \
        const int _off = (SV) * 16 + kh * 8; \
        ahi = *(const short8*)(xh + n1 * 72 + _off); \
        alo = *(const short8*)(xl + n1 * 72 + _off); \
    } else { \
        const int _off = ((SV) - 4) * 16 + kh * 8; \
        ahi = *(const short8*)(h1hi + n1 * 520 + _off); \
        alo = *(const short8*)(h1lo + n1 * 520 + _off); \
    } } while (0)

// 6 MFMAs of one L1 k-step: Q0=hi g0, Q1=lo g0, Q2=hi g1, Q3=lo g1
#define L1_MFMAS(Q0, Q1, Q2, Q3) do { \
    MFMA32(P0, ahi, Q0); MFMA32(P1, ahi, Q2); \
    MFMA32(P0, alo, Q0); MFMA32(P1, alo, Q2); \
    MFMA32(P0, ahi, Q1); MFMA32(P1, ahi, Q3); \
} while (0)

#define L2_LOAD_A(SV) do { \
    if ((SV) < 16) { \
        const int _off = (SV) * 32 + quad * 8; \
        short8 _a  = *(const short8*)(h1hi + row2 * 520 + _off); \
        short8 _al = *(const short8*)(h1lo + row2 * 520 + _off); \
        short8 _msk = _a >> 15; \
        ahi = _a & ~_msk; alo = _al & ~_msk; \
    } else { \
        const int _off = ((SV) - 16) * 32 + quad * 8; \
        ahi = *(const short8*)(h2hi + cur * 4352 + row2 * 136 + _off); \
        alo = *(const short8*)(h2lo + cur * 4352 + row2 * 136 + _off); \
    } } while (0)

#define L2_MFMAS(Q0, Q1, Q2, Q3, Q4, Q5, Q6, Q7) do { \
    MFMA16(a20, ahi, Q0); MFMA16(a21, ahi, Q2); MFMA16(a22, ahi, Q4); MFMA16(a23, ahi, Q6); \
    MFMA16(a20, alo, Q0); MFMA16(a21, alo, Q2); MFMA16(a22, alo, Q4); MFMA16(a23, alo, Q6); \
    MFMA16(a20, ahi, Q1); MFMA16(a21, ahi, Q3); MFMA16(a22, ahi, Q5); MFMA16(a23, ahi, Q7); \
} while (0)

#define L3_LOAD_A(SV) do { \
    if ((SV) < 4) { \
        const int _off = (SV) * 32 + quad * 8; \
        short8 _a  = *(const short8*)(h2hi + nxt * 4352 + row3 * 136 + _off); \
        short8 _al = *(const short8*)(h2lo + nxt * 4352 + row3 * 136 + _off); \
        short8 _msk = _a >> 15; \
        ahi = _a & ~_msk; alo = _al & ~_msk; \
    } else { \
        const int _off = ((SV) - 4) * 32 + quad * 8; \
        ahi = *(const short8*)(h3hi + cur * 2304 + row3 * 72 + _off); \
        alo = *(const short8*)(h3lo + cur * 2304 + row3 * 72 + _off); \
    } } while (0)

#define L3_MFMAS(Q0, Q1, Q2, Q3, Q4, Q5, Q6, Q7) do { \
    MFMA16(a30, ahi, Q0); MFMA16(a31, ahi, Q2); MFMA16(a32, ahi, Q4); MFMA16(a33, ahi, Q6); \
    MFMA16(a30, alo, Q0); MFMA16(a31, alo, Q2); MFMA16(a32, alo, Q4); MFMA16(a33, alo, Q6); \
    MFMA16(a30, ahi, Q1); MFMA16(a31, ahi, Q3); MFMA16(a32, ahi, Q5); MFMA16(a33, ahi, Q7); \
} while (0)

// ---- Fused Siamese 3-layer LSTM. 256 WGs x 1024 thr (16 waves, 4/SIMD), 135KB LDS.
// Round-10: latency-bound weight stream attacked three ways.
//  (1) Full 4-frag depth-1 prefetch in L1 (lo frags were loaded in-iteration) via
//      manual unroll-2 ping-pong register sets (no copy v_movs) in L1/L2/L3 k-loops.
//  (2) LDS-only raw barriers (lgkmcnt(0)+s_barrier): __syncthreads' vmcnt(0) drain
//      was killing all in-flight weight loads 4x per timestep. All cross-wave comm
//      is via LDS, so vmcnt need not drain.
//  (3) Each phase's entry prefetch issued across the preceding barrier/epilogue
//      (pass1 before pass0 epilogue; L2 right after barrier C; L3 before barrier D;
//      next-t pass0 before barrier E, persistent across the t-backedge).
__global__ __launch_bounds__(1024, 4) void lstm3_v3(
    const float* __restrict__ x1, const float* __restrict__ x2,
    const unsigned short* __restrict__ l1w, const unsigned short* __restrict__ l2w,
    const unsigned short* __restrict__ l3w,
    const float* __restrict__ b1, const float* __restrict__ b2, const float* __restrict__ b3,
    float* __restrict__ dbuf)
{
    extern __shared__ unsigned short sm[];
    unsigned short* h1hi = sm;                    // [32][520]
    unsigned short* h1lo = h1hi + 32 * 520;
    unsigned short* h2hi = h1lo + 32 * 520;       // [2][32][136]
    unsigned short* h2lo = h2hi + 2 * 32 * 136;
    unsigned short* h3hi = h2lo + 2 * 32 * 136;   // [2][32][72]
    unsigned short* h3lo = h3hi + 2 * 32 * 72;
    unsigned short* xhi  = h3lo + 2 * 32 * 72;    // [2][32][72] double-buffered
    unsigned short* xlo  = xhi  + 2 * 32 * 72;

    const int tid  = threadIdx.x;
    const int wv   = tid >> 6;
    const int lane = tid & 63;
    const int wg   = blockIdx.x;
    const int samp0 = wg * 16;

    {
        unsigned int* p = (unsigned int*)sm;
        for (int i = tid; i < 29952; i += 1024) p[i] = 0u;
    }

    // L1 lane mapping (32x32)
    const int n1 = lane & 31;
    const int kh = lane >> 5;
    const int u1 = wv * 32 + n1;
    // L2/L3 lane mapping (16x16)
    const int n2   = lane & 15;
    const int quad = lane >> 4;
    const int mt2  = wv >> 3, cg2 = wv & 7;
    const int u2   = cg2 * 16 + n2;
    const int row2 = mt2 * 16 + n2;
    const int mt3  = (wv >> 2) & 1, cg3 = wv & 3;
    const int u3   = cg3 * 16 + n2;
    const int row3 = mt3 * 16 + n2;

    float c1[16], c2[4], c3[4];
    #pragma unroll
    for (int r = 0; r < 16; ++r) c1[r] = 0.0f;
    #pragma unroll
    for (int r = 0; r < 4; ++r) { c2[r] = 0.0f; c3[r] = 0.0f; }

    const unsigned short* B1p = l1w + wv * 4096 + lane * 8;
    const unsigned short* B2p = l2w + cg2 * 4096 + lane * 8;
    const unsigned short* B3p = l3w + cg3 * 4096 + lane * 8;

    // pass-0 entry prefetch, persistent across the t-loop backedge.
    // t=0: rev=false -> s0=0, gate pair (i,f) at gate-offset 0.
    short8 p0A0, p0A1, p0A2, p0A3;
    FETCH4(B1p, p0A0, p0A1, p0A2, p0A3);

    // stage x_0 into parity-0 buffer (prologue)
    for (int e = tid; e < 2048; e += 1024) {
        int b = e >> 6, f = e & 63;
        const float* __restrict__ xp = (b < 16) ? x1 : x2;
        float v = (f < 58) ? xp[(samp0 + (b & 15)) * 1740 + f * 30 + 0] : 0.0f;
        unsigned short hi = f2b(v);
        xhi[b * 72 + f] = hi;
        xlo[b * 72 + f] = f2b(v - b2f(hi));
    }
    bar_lds();

    int cur = 0;
    #pragma unroll 1
    for (int t = 0; t < NTIME; ++t) {
        const bool rev = (t & 1);
        const int nxt = cur ^ 1;
        const unsigned short* xh = xhi + (t & 1) * 2304;
        const unsigned short* xl = xlo + (t & 1) * 2304;

        float i1[16];                 // sigmoid(i-gate), carried pass0 -> pass1
        short8 p1A0, p1A1, p1A2, p1A3; // pass1 entry frags (filled before pass0 epilogue)

        // ============ L1 pass 0: gates i,f; k = [x 64 | h1 512], 36 ksteps ============
        {
            f32x16 P0, P1;
            {
                float bg0 = b1[u1], bg1 = b1[512 + u1];
                #pragma unroll
                for (int r = 0; r < 16; ++r) { P0[r] = bg0; P1[r] = bg1; }
            }
            short8 p0B0, p0B1, p0B2, p0B3;
            #pragma unroll 1
            for (int ss = 0; ss < 36; ss += 2) {
                const int sa = rev ? (35 - ss) : ss;
                const int sb = rev ? (34 - ss) : (ss + 1);
                {
                    short8 ahi, alo;
                    L1_LOAD_A(sa);
                    FETCH4(B1p + sb * 65536, p0B0, p0B1, p0B2, p0B3);
                    L1_MFMAS(p0A0, p0A1, p0A2, p0A3);
                }
                {
                    short8 ahi, alo;
                    L1_LOAD_A(sb);
                    if (ss + 2 < 36) {
                        const int sc = rev ? (33 - ss) : (ss + 2);
                        FETCH4(B1p + sc * 65536, p0A0, p0A1, p0A2, p0A3);
                    }
                    L1_MFMAS(p0B0, p0B1, p0B2, p0B3);
                }
            }
            // hoisted pass-1 entry prefetch: latency hides under the epilogue below
            FETCH4(B1p + (rev ? 35 : 0) * 65536 + 2048, p1A0, p1A1, p1A2, p1A3);
            #pragma unroll
            for (int r = 0; r < 16; ++r) {
                i1[r] = sigf(P0[r]);
                c1[r] *= sigf(P1[r]);      // c = F*c (I*G added in pass 1)
            }
        }

        // ============ L1 pass 1: gates g,o ============
        {
            f32x16 P0, P1;
            {
                float bg0 = b1[1024 + u1], bg1 = b1[1536 + u1];
                #pragma unroll
                for (int r = 0; r < 16; ++r) { P0[r] = bg0; P1[r] = bg1; }
            }
            short8 p1B0, p1B1, p1B2, p1B3;
            #pragma unroll 1
            for (int ss = 0; ss < 36; ss += 2) {
                const int sa = rev ? (35 - ss) : ss;
                const int sb = rev ? (34 - ss) : (ss + 1);
                {
                    short8 ahi, alo;
                    L1_LOAD_A(sa);
                    FETCH4(B1p + sb * 65536 + 2048, p1B0, p1B1, p1B2, p1B3);
                    L1_MFMAS(p1A0, p1A1, p1A2, p1A3);
                }
                {
                    short8 ahi, alo;
                    L1_LOAD_A(sb);
                    if (ss + 2 < 36) {
                        const int sc = rev ? (33 - ss) : (ss + 2);
                        FETCH4(B1p + sc * 65536 + 2048, p1A0, p1A1, p1A2, p1A3);
                    }
                    L1_MFMAS(p1B0, p1B1, p1B2, p1B3);
                }
            }
            bar_lds();   // B: all reads of h1(t-1)/x(t) done
            #pragma unroll
            for (int r = 0; r < 16; ++r) {
                float G = tanhfast(P0[r]);
                float O = sigf(P1[r]);
                float c = c1[r] + i1[r] * G;
                c1[r] = c;
                float h = O * tanhfast(c);
                int row = (r & 3) + 8 * (r >> 2) + 4 * kh;   // verified 32x32 C-map
                unsigned short hh = f2b(h);
                h1hi[row * 520 + u1] = hh;
                h1lo[row * 520 + u1] = f2b(h - b2f(hh));
            }
        }
        bar_lds();   // C: h1(t) visible

        // L2 entry prefetch issued immediately; its latency overlaps the x staging.
        short8 qA0, qA1, qA2, qA3, qA4, qA5, qA6, qA7;
        FETCH8(B2p + (rev ? 19 : 0) * 32768, qA0, qA1, qA2, qA3, qA4, qA5, qA6, qA7);

        // prefetch x(t+1) into the other parity buffer (overlaps L2 k-loop)
        if (t + 1 < NTIME) {
            unsigned short* xh2 = xhi + ((t + 1) & 1) * 2304;
            unsigned short* xl2 = xlo + ((t + 1) & 1) * 2304;
            #pragma unroll
            for (int e = tid; e < 2048; e += 1024) {
                int b = e >> 6, f = e & 63;
                const float* __restrict__ xp = (b < 16) ? x1 : x2;
                float v = (f < 58) ? xp[(samp0 + (b & 15)) * 1740 + f * 30 + (t + 1)] : 0.0f;
                unsigned short hi = f2b(v);
                xh2[b * 72 + f] = hi;
                xl2[b * 72 + f] = f2b(v - b2f(hi));
            }
        }

        // L3 entry frags (filled before barrier D, consumed after)
        short8 rA0, rA1, rA2, rA3, rA4, rA5, rA6, rA7;

        // ============ L2: 16x16x32, k = [relu(h1) 512 | h2 128], 20 ksteps ============
        {
            f32x4 a20, a21, a22, a23;
            {
                float bg0 = b2[u2], bg1 = b2[128 + u2], bg2 = b2[256 + u2], bg3 = b2[384 + u2];
                a20 = (f32x4){bg0, bg0, bg0, bg0};
                a21 = (f32x4){bg1, bg1, bg1, bg1};
                a22 = (f32x4){bg2, bg2, bg2, bg2};
                a23 = (f32x4){bg3, bg3, bg3, bg3};
            }
            short8 qB0, qB1, qB2, qB3, qB4, qB5, qB6, qB7;
            #pragma unroll 1
            for (int ss = 0; ss < 20; ss += 2) {
                const int sa = rev ? (19 - ss) : ss;
                const int sb = rev ? (18 - ss) : (ss + 1);
                {
                    short8 ahi, alo;
                    L2_LOAD_A(sa);
                    FETCH8(B2p + sb * 32768, qB0, qB1, qB2, qB3, qB4, qB5, qB6, qB7);
                    L2_MFMAS(qA0, qA1, qA2, qA3, qA4, qA5, qA6, qA7);
                }
                {
                    short8 ahi, alo;
                    L2_LOAD_A(sb);
                    if (ss + 2 < 20) {
                        const int sc = rev ? (17 - ss) : (ss + 2);
                        FETCH8(B2p + sc * 32768, qA0, qA1, qA2, qA3, qA4, qA5, qA6, qA7);
                    }
                    L2_MFMAS(qB0, qB1, qB2, qB3, qB4, qB5, qB6, qB7);
                }
            }
            // L3 entry prefetch: issue before the L2 epilogue + barrier D for cover
            if (wv < 8) {
                FETCH8(B3p + (rev ? 5 : 0) * 16384, rA0, rA1, rA2, rA3, rA4, rA5, rA6, rA7);
            }
            #pragma unroll
            for (int r = 0; r < 4; ++r) {
                float I = sigf(a20[r]);
                float F = sigf(a21[r]);
                float G = tanhfast(a22[r]);
                float O = sigf(a23[r]);
                float c = F * c2[r] + I * G;
                c2[r] = c;
                float h = O * tanhfast(c);
                int row = mt2 * 16 + quad * 4 + r;
                unsigned short hh = f2b(h);
                h2hi[nxt * 4352 + row * 136 + u2] = hh;
                h2lo[nxt * 4352 + row * 136 + u2] = f2b(h - b2f(hh));
            }
        }
        bar_lds();   // D: h2(t) + x(t+1) visible

        // ============ L3: 16x16x32, k = [relu(h2) 128 | h3 64], 6 ksteps (waves 0-7) ====
        if (wv < 8) {
            f32x4 a30, a31, a32, a33;
            {
                float bg0 = b3[u3], bg1 = b3[64 + u3], bg2 = b3[128 + u3], bg3 = b3[192 + u3];
                a30 = (f32x4){bg0, bg0, bg0, bg0};
                a31 = (f32x4){bg1, bg1, bg1, bg1};
                a32 = (f32x4){bg2, bg2, bg2, bg2};
                a33 = (f32x4){bg3, bg3, bg3, bg3};
            }
            short8 rB0, rB1, rB2, rB3, rB4, rB5, rB6, rB7;
            #pragma unroll 1
            for (int ss = 0; ss < 6; ss += 2) {
                const int sa = rev ? (5 - ss) : ss;
                const int sb = rev ? (4 - ss) : (ss + 1);
                {
                    short8 ahi, alo;
                    L3_LOAD_A(sa);
                    FETCH8(B3p + sb * 16384, rB0, rB1, rB2, rB3, rB4, rB5, rB6, rB7);
                    L3_MFMAS(rA0, rA1, rA2, rA3, rA4, rA5, rA6, rA7);
                }
                {
                    short8 ahi, alo;
                    L3_LOAD_A(sb);
                    if (ss + 2 < 6) {
                        const int sc = rev ? (3 - ss) : (ss + 2);
                        FETCH8(B3p + sc * 16384, rA0, rA1, rA2, rA3, rA4, rA5, rA6, rA7);
                    }
                    L3_MFMAS(rB0, rB1, rB2, rB3, rB4, rB5, rB6, rB7);
                }
            }
            #pragma unroll
            for (int r = 0; r < 4; ++r) {
                float I = sigf(a30[r]);
                float F = sigf(a31[r]);
                float G = tanhfast(a32[r]);
                float O = sigf(a33[r]);
                float c = F * c3[r] + I * G;
                c3[r] = c;
                float h = O * tanhfast(c);
                int row = mt3 * 16 + quad * 4 + r;
                unsigned short hh = f2b(h);
                h3hi[nxt * 2304 + row * 72 + u3] = hh;
                h3lo[nxt * 2304 + row * 72 + u3] = f2b(h - b2f(hh));
            }
        }

        // next-t pass-0 entry prefetch: issued before barrier E + d-write,
        // survives the backedge (and the raw barriers do not drain vmcnt).
        if (t + 1 < NTIME) {
            // rev(t+1) = !rev: next pass0 starts at s=35 when t is even, s=0 when odd
            FETCH4(B1p + (rev ? 0 : 35) * 65536, p0A0, p0A1, p0A2, p0A3);
        }
        bar_lds();   // E: h3(t) visible

        // d = |relu(h3_x1) - relu(h3_x2)| -> global
        {
            int b = tid >> 6, u = tid & 63;
            float ha = b2f(h3hi[nxt * 2304 + b * 72 + u]) + b2f(h3lo[nxt * 2304 + b * 72 + u]);
            float hb = b2f(h3hi[nxt * 2304 + (16 + b) * 72 + u]) + b2f(h3lo[nxt * 2304 + (16 + b) * 72 + u]);
            dbuf[(size_t)(samp0 + b) * 1920 + t * 64 + u] = fabsf(fmaxf(ha, 0.0f) - fmaxf(hb, 0.0f));
        }
        cur = nxt;
    }
}

// ---- FC head v2
__global__ __launch_bounds__(512) void head_v2(
    const float* __restrict__ dg,
    const float4* __restrict__ WT1, const float* __restrict__ bf1,
    const float4* __restrict__ WT2, const float* __restrict__ bf2,
    const float* __restrict__ Wf3, const float* __restrict__ bf3,
    const float* __restrict__ Wf4, const float* __restrict__ bf4,
    float* __restrict__ out)
{
    extern __shared__ float hds[];
    float* ds = hds;                  // [16][1928] during fc1
    float* a1 = hds;                  // [16][1032] overlay after fc1
    float* a2 = a1 + 16 * 1032;       // [16][520]
    float* a3 = a2 + 16 * 520;        // [16][16]

    const int tid = threadIdx.x;
    const int samp0 = blockIdx.x * 16;

    for (int e = tid; e < 16 * 480; e += 512) {
        int b = e / 480, jc = e - b * 480;
        const float* src = dg + (size_t)(samp0 + b) * 1920 + jc * 4;
        float* dst = ds + b * 1928 + jc * 4;
        dst[0] = src[0]; dst[1] = src[1]; dst[2] = src[2]; dst[3] = src[3];
    }
    __syncthreads();

    const int w = tid >> 6, lane = tid & 63;
    const int oA = w * 128 + lane, oB = oA + 64;
    float accA[16], accB[16];
    {
        float bA = (oA < 960) ? bf1[oA] : 0.0f;
        float bB = (oB < 960) ? bf1[oB] : 0.0f;
        #pragma unroll
        for (int r = 0; r < 16; ++r) { accA[r] = bA; accB[r] = bB; }
    }
    #pragma unroll 2
    for (int kc = 0; kc < 480; ++kc) {
        float4 wA = WT1[kc * 1024 + oA];
        float4 wB = WT1[kc * 1024 + oB];
        #pragma unroll
        for (int r = 0; r < 16; ++r) {
            float4 d4 = ((const float4*)(ds + r * 1928))[kc];
            accA[r] += d4.x * wA.x + d4.y * wA.y + d4.z * wA.z + d4.w * wA.w;
            accB[r] += d4.x * wB.x + d4.y * wB.y + d4.z * wB.z + d4.w * wB.w;
        }
    }
    __syncthreads();
    #pragma unroll
    for (int r = 0; r < 16; ++r) {
        a1[r * 1032 + oA] = fmaxf(accA[r], 0.0f);
        a1[r * 1032 + oB] = fmaxf(accB[r], 0.0f);
    }
    __syncthreads();

    const int o2 = tid;
    float acc2[16];
    {
        float b = (o2 < 480) ? bf2[o2] : 0.0f;
        #pragma unroll
        for (int r = 0; r < 16; ++r) acc2[r] = b;
    }
    #pragma unroll 2
    for (int kc = 0; kc < 256; ++kc) {
        float4 w4 = WT2[kc * 512 + o2];
        #pragma unroll
        for (int r = 0; r < 16; ++r) {
            float4 a4 = ((const float4*)(a1 + r * 1032))[kc];
            acc2[r] += a4.x * w4.x + a4.y * w4.y + a4.z * w4.z + a4.w * w4.w;
        }
    }
    #pragma unroll
    for (int r = 0; r < 16; ++r) a2[r * 520 + o2] = fmaxf(acc2[r], 0.0f);
    __syncthreads();

    if (tid < 256) {
        int o = tid & 15, r = tid >> 4;
        float acc = bf3[o];
        const float4* wr = (const float4*)(Wf3 + (size_t)o * 480);
        const float4* av = (const float4*)(a2 + r * 520);
        #pragma unroll 4
        for (int kc = 0; kc < 120; ++kc) {
            float4 a4 = av[kc];
            float4 w4 = wr[kc];
            acc += a4.x * w4.x + a4.y * w4.y + a4.z * w4.z + a4.w * w4.w;
        }
        a3[r * 16 + o] = fmaxf(acc, 0.0f);
    }
    __syncthreads();

    if (tid < 16) {
        float acc = bf4[0];
        #pragma unroll
        for (int k = 0; k < 16; ++k) acc += a3[tid * 16 + k] * Wf4[k];
        out[samp0 + tid] = acc;
    }
}

extern "C" void kernel_launch(void* const* d_in, const int* in_sizes, int n_in,
                              void* d_out, int out_size, void* d_ws, size_t ws_size,
                              hipStream_t stream) {
    const float* x1   = (const float*)d_in[0];
    const float* x2   = (const float*)d_in[1];
    const float* Wih1 = (const float*)d_in[2];
    const float* Whh1 = (const float*)d_in[3];
    const float* b1   = (const float*)d_in[4];
    const float* Wih2 = (const float*)d_in[5];
    const float* Whh2 = (const float*)d_in[6];
    const float* b2   = (const float*)d_in[7];
    const float* Wih3 = (const float*)d_in[8];
    const float* Whh3 = (const float*)d_in[9];
    const float* b3   = (const float*)d_in[10];
    const float* Wf1  = (const float*)d_in[11];
    const float* bf1  = (const float*)d_in[12];
    const float* Wf2  = (const float*)d_in[13];
    const float* bf2  = (const float*)d_in[14];
    const float* Wf3  = (const float*)d_in[15];
    const float* bf3  = (const float*)d_in[16];
    const float* Wf4  = (const float*)d_in[17];
    const float* bf4  = (const float*)d_in[18];

    float* wsf = (float*)d_ws;
    float* dbuf = wsf;                                         // 4096*1920 = 7,864,320 f32
    unsigned short* l1w = (unsigned short*)(wsf + 7864320);    // 36*65536  = 2,359,296 us
    unsigned short* l2w = l1w + 2359296;                       // 20*8*4096 =   655,360 us
    unsigned short* l3w = l2w + 655360;                        //  6*4*4096 =    98,304 us
    float4* WT1 = (float4*)(wsf + 9420800);                    // 480*1024 float4
    float4* WT2 = WT1 + 480 * 1024;                            // 256*512  float4
    float* out = (float*)d_out;

    prep_w32<<<(36 * 65536) / 256, 256, 0, stream>>>(Wih1, Whh1, l1w);
    prep_w16<<<(20 * 8 * 4096) / 256, 256, 0, stream>>>(Wih2, Whh2, l2w, 128, 512, 512, 128, 8, 20);
    prep_w16<<<(6 * 4 * 4096) / 256, 256, 0, stream>>>(Wih3, Whh3, l3w, 64, 128, 128, 64, 4, 6);
    pack_wt1<<<(480 * 1024) / 256, 256, 0, stream>>>(Wf1, WT1);
    pack_wt2<<<(256 * 512) / 256, 256, 0, stream>>>(Wf2, WT2);

    (void)hipFuncSetAttribute((const void*)lstm3_v3,
                              hipFuncAttributeMaxDynamicSharedMemorySize, 138240);
    lstm3_v3<<<256, 1024, 138240, stream>>>(x1, x2, l1w, l2w, l3w, b1, b2, b3, dbuf);

    (void)hipFuncSetAttribute((const void*)head_v2,
                              hipFuncAttributeMaxDynamicSharedMemorySize, 16 * 1928 * 4);
    head_v2<<<256, 512, 16 * 1928 * 4, stream>>>(dbuf, WT1, bf1, WT2, bf2,
                                                 Wf3, bf3, Wf4, bf4, out);
}

// Round 2
// 4263.907 us; speedup vs baseline: 1.0193x; 1.0193x over previous
//
#include <hip/hip_runtime.h>

#define NTIME 30
#define NB 4096

typedef __attribute__((ext_vector_type(8))) short short8;
typedef __attribute__((ext_vector_type(4))) float f32x4;
typedef __attribute__((ext_vector_type(16))) float f32x16;

__device__ __forceinline__ unsigned short f2b(float f) {
    unsigned int u = __float_as_uint(f);
    u = u + 0x7FFFu + ((u >> 16) & 1u);        // RNE to bf16
    return (unsigned short)(u >> 16);
}
__device__ __forceinline__ float b2f(unsigned short s) {
    return __uint_as_float(((unsigned int)s) << 16);
}
__device__ __forceinline__ float sigf(float x)     { return 1.0f / (1.0f + __expf(-x)); }
__device__ __forceinline__ float tanhfast(float x) { return 1.0f - 2.0f / (__expf(2.0f * x) + 1.0f); }

// LDS-only barrier: all cross-wave communication inside lstm3 is via LDS, so we
// only need lgkmcnt(0)+s_barrier. Does NOT drain vmcnt -> global weight
// prefetches stay in flight across phase boundaries.
__device__ __forceinline__ void bar_lds() {
    asm volatile("s_waitcnt lgkmcnt(0)" ::: "memory");
    __builtin_amdgcn_s_barrier();
    asm volatile("" ::: "memory");
}

// ---- L1 weight pack: 32x32x16 B-frags, bf16 hi/lo planes (layout unchanged, validated).
__global__ __launch_bounds__(256) void prep_w32(const float* __restrict__ Wih,
                                                const float* __restrict__ Whh,
                                                unsigned short* __restrict__ out)
{
    int e = blockIdx.x * 256 + threadIdx.x;
    if (e >= 36 * 65536) return;
    int j     = e & 7;
    int lane  = (e >> 3) & 63;
    int plane = (e >> 9) & 1;
    int g     = (e >> 10) & 3;
    int w     = (e >> 12) & 15;
    int s     = e >> 16;
    int n = lane & 31, kh = lane >> 5;
    int unit = w * 32 + n;
    int k = s * 16 + kh * 8 + j;
    int row = g * 512 + unit;
    float v = 0.0f;
    if (k < 64) { if (k < 58) v = Wih[row * 58 + k]; }
    else        { v = Whh[row * 512 + (k - 64)]; }
    unsigned short hi = f2b(v);
    out[e] = plane ? f2b(v - b2f(hi)) : hi;
}

// ---- L2/L3 weight pack: 16x16x32 B-frags (validated layout).
__global__ __launch_bounds__(256) void prep_w16(const float* __restrict__ Wih,
                                                const float* __restrict__ Whh,
                                                unsigned short* __restrict__ out,
                                                int H, int KI, int KIp, int KH, int CG, int KS)
{
    int e = blockIdx.x * 256 + threadIdx.x;
    if (e >= KS * CG * 4096) return;
    int j     = e & 7;
    int lane  = (e >> 3) & 63;
    int plane = (e >> 9) & 1;
    int g     = (e >> 10) & 3;
    int rest  = e >> 12;
    int cg = rest % CG;
    int s  = rest / CG;
    int n = lane & 15, q = lane >> 4;
    int unit = cg * 16 + n;
    int k = s * 32 + q * 8 + j;
    int row = g * H + unit;
    float v = 0.0f;
    if (k < KIp) { if (k < KI) v = Wih[row * KI + k]; }
    else         { v = Whh[row * KH + (k - KIp)]; }
    unsigned short hi = f2b(v);
    out[e] = plane ? f2b(v - b2f(hi)) : hi;
}

// ---- Head weight transposes (o-fastest float4 blocks)
__global__ __launch_bounds__(256) void pack_wt1(const float* __restrict__ Wf1, float4* __restrict__ WT1)
{
    int e = blockIdx.x * 256 + threadIdx.x;
    if (e >= 480 * 1024) return;
    int kc = e >> 10, o = e & 1023;
    float4 v = {0.0f, 0.0f, 0.0f, 0.0f};
    if (o < 960) {
        const float* p = Wf1 + (size_t)o * 1920 + kc * 4;
        v.x = p[0]; v.y = p[1]; v.z = p[2]; v.w = p[3];
    }
    WT1[e] = v;
}
__global__ __launch_bounds__(256) void pack_wt2(const float* __restrict__ Wf2, float4* __restrict__ WT2)
{
    int e = blockIdx.x * 256 + threadIdx.x;
    if (e >= 256 * 512) return;
    int kc = e >> 9, o = e & 511;
    float4 v = {0.0f, 0.0f, 0.0f, 0.0f};
    if (o < 480) {
        int k = kc * 4;
        v.x = (k + 0 < 960) ? Wf2[(size_t)o * 960 + k + 0] : 0.0f;
        v.y = (k + 1 < 960) ? Wf2[(size_t)o * 960 + k + 1] : 0.0f;
        v.z = (k + 2 < 960) ? Wf2[(size_t)o * 960 + k + 2] : 0.0f;
        v.w = (k + 3 < 960) ? Wf2[(size_t)o * 960 + k + 3] : 0.0f;
    }
    WT2[e] = v;
}

#define MFMA32(A, X, B) A = __builtin_amdgcn_mfma_f32_32x32x16_bf16((X), (B), (A), 0, 0, 0)
#define MFMA16(A, X, B) A = __builtin_amdgcn_mfma_f32_16x16x32_bf16((X), (B), (A), 0, 0, 0)

// L1 A-fragment load (x for s<4, h1 otherwise)
#define L1_LOAD_A(SV) do { \
    if ((SV) < 4) { \
        const int _off = (SV) * 16 + kh * 8; \
        ahi = *(const short8*)(xh + n1 * 72 + _off); \
        alo = *(const short8*)(xl + n1 * 72 + _off); \
    } else { \
        const int _off = ((SV) - 4) * 16 + kh * 8; \
        ahi = *(const short8*)(h1hi + n1 * 520 + _off); \
        alo = *(const short8*)(h1lo + n1 * 520 + _off); \
    } } while (0)

// one L1 k-step of a single gate: 3 MFMAs on one acc chain, then refill the
// just-freed set with the step 3 ahead (depth-3 rotation; no copy movs).
#define L1_SUB(WH, WL, IDX, GOFF) do { \
    const int _s = rev ? (35 - (ss + (IDX))) : (ss + (IDX)); \
    short8 ahi, alo; \
    L1_LOAD_A(_s); \
    MFMA32(P, ahi, WH); \
    MFMA32(P, alo, WH); \
    MFMA32(P, ahi, WL); \
    if (ss + (IDX) + 3 < 36) { \
        const int _sn = rev ? (35 - (ss + (IDX) + 3)) : (ss + (IDX) + 3); \
        const unsigned short* _bb = B1p + _sn * 65536 + (GOFF); \
        WH = *(const short8*)(_bb); \
        WL = *(const short8*)(_bb + 512); \
    } } while (0)

#define L1_KLOOP(GOFF) \
    _Pragma("unroll 1") \
    for (int ss = 0; ss < 36; ss += 3) { \
        L1_SUB(w0h, w0l, 0, GOFF); \
        L1_SUB(w1h, w1l, 1, GOFF); \
        L1_SUB(w2h, w2l, 2, GOFF); \
    }

// entry prefetch of the first 3 k-steps of a pass. RV = direction of that pass.
#define L1_ENTRY(GOFF, RV) do { \
    const int _s0 = (RV) ? 35 : 0, _s1 = (RV) ? 34 : 1, _s2 = (RV) ? 33 : 2; \
    const unsigned short* _b0 = B1p + _s0 * 65536 + (GOFF); \
    const unsigned short* _b1 = B1p + _s1 * 65536 + (GOFF); \
    const unsigned short* _b2 = B1p + _s2 * 65536 + (GOFF); \
    w0h = *(const short8*)(_b0); w0l = *(const short8*)(_b0 + 512); \
    w1h = *(const short8*)(_b1); w1l = *(const short8*)(_b1 + 512); \
    w2h = *(const short8*)(_b2); w2l = *(const short8*)(_b2 + 512); \
} while (0)

#define L2_LOAD_A(SV) do { \
    if ((SV) < 16) { \
        const int _off = (SV) * 32 + quad * 8; \
        short8 _a  = *(const short8*)(h1hi + row2 * 520 + _off); \
        short8 _al = *(const short8*)(h1lo + row2 * 520 + _off); \
        short8 _msk = _a >> 15; \
        ahi = _a & ~_msk; alo = _al & ~_msk; \
    } else { \
        const int _off = ((SV) - 16) * 32 + quad * 8; \
        ahi = *(const short8*)(h2hi + cur * 4352 + row2 * 136 + _off); \
        alo = *(const short8*)(h2lo + cur * 4352 + row2 * 136 + _off); \
    } } while (0)

// one L2 k-step of a 2-gate pass (Q0/Q1 = gateA hi/lo, Q2/Q3 = gateB hi/lo)
#define L2_SUB(Q0, Q1, Q2, Q3, IDX, GOFF) do { \
    const int _s = rev ? (19 - (ss + (IDX))) : (ss + (IDX)); \
    short8 ahi, alo; \
    L2_LOAD_A(_s); \
    MFMA16(A0, ahi, Q0); \
    MFMA16(A1, ahi, Q2); \
    MFMA16(A0, alo, Q0); \
    MFMA16(A1, alo, Q2); \
    MFMA16(A0, ahi, Q1); \
    MFMA16(A1, ahi, Q3); \
    if (ss + (IDX) + 2 < 20) { \
        const int _sn = rev ? (19 - (ss + (IDX) + 2)) : (ss + (IDX) + 2); \
        const unsigned short* _bb = B2p + _sn * 32768 + (GOFF); \
        Q0 = *(const short8*)(_bb); \
        Q1 = *(const short8*)(_bb + 512); \
        Q2 = *(const short8*)(_bb + 1024); \
        Q3 = *(const short8*)(_bb + 1536); \
    } } while (0)

#define L2_ENTRY(GOFF) do { \
    const int _s0 = rev ? 19 : 0, _s1 = rev ? 18 : 1; \
    const unsigned short* _b0 = B2p + _s0 * 32768 + (GOFF); \
    const unsigned short* _b1 = B2p + _s1 * 32768 + (GOFF); \
    qa0 = *(const short8*)(_b0);        qa1 = *(const short8*)(_b0 + 512); \
    qa2 = *(const short8*)(_b0 + 1024); qa3 = *(const short8*)(_b0 + 1536); \
    qb0 = *(const short8*)(_b1);        qb1 = *(const short8*)(_b1 + 512); \
    qb2 = *(const short8*)(_b1 + 1024); qb3 = *(const short8*)(_b1 + 1536); \
} while (0)

#define L3_LOAD_A(SV) do { \
    if ((SV) < 4) { \
        const int _off = (SV) * 32 + quad * 8; \
        short8 _a  = *(const short8*)(h2hi + nxt * 4352 + row3 * 136 + _off); \
        short8 _al = *(const short8*)(h2lo + nxt * 4352 + row3 * 136 + _off); \
        short8 _msk = _a >> 15; \
        ahi = _a & ~_msk; alo = _al & ~_msk; \
    } else { \
        const int _off = ((SV) - 4) * 32 + quad * 8; \
        ahi = *(const short8*)(h3hi + cur * 2304 + row3 * 72 + _off); \
        alo = *(const short8*)(h3lo + cur * 2304 + row3 * 72 + _off); \
    } } while (0)

#define L3_SUB(Q0, Q1, Q2, Q3, IDX, GOFF) do { \
    const int _s = rev ? (5 - (ss + (IDX))) : (ss + (IDX)); \
    short8 ahi, alo; \
    L3_LOAD_A(_s); \
    MFMA16(A0, ahi, Q0); \
    MFMA16(A1, ahi, Q2); \
    MFMA16(A0, alo, Q0); \
    MFMA16(A1, alo, Q2); \
    MFMA16(A0, ahi, Q1); \
    MFMA16(A1, ahi, Q3); \
    if (ss + (IDX) + 2 < 6) { \
        const int _sn = rev ? (5 - (ss + (IDX) + 2)) : (ss + (IDX) + 2); \
        const unsigned short* _bb = B3p + _sn * 16384 + (GOFF); \
        Q0 = *(const short8*)(_bb); \
        Q1 = *(const short8*)(_bb + 512); \
        Q2 = *(const short8*)(_bb + 1024); \
        Q3 = *(const short8*)(_bb + 1536); \
    } } while (0)

#define L3_ENTRY_B(GOFF) do { \
    const int _s1 = rev ? 4 : 1; \
    const unsigned short* _b1 = B3p + _s1 * 16384 + (GOFF); \
    rb0 = *(const short8*)(_b1);        rb1 = *(const short8*)(_b1 + 512); \
    rb2 = *(const short8*)(_b1 + 1024); rb3 = *(const short8*)(_b1 + 1536); \
} while (0)

#define L3_ENTRY_A(GOFF) do { \
    const int _s0 = rev ? 5 : 0; \
    const unsigned short* _b0 = B3p + _s0 * 16384 + (GOFF); \
    ra0 = *(const short8*)(_b0);        ra1 = *(const short8*)(_b0 + 512); \
    ra2 = *(const short8*)(_b0 + 1024); ra3 = *(const short8*)(_b0 + 1536); \
} while (0)

// ---- Fused Siamese 3-layer LSTM. 256 WGs x 1024 thr (16 waves, 4/SIMD), 135KB LDS.
// Round-11 (v4): register-diet deep pipeline. Round-10's ping-pong sets blew the
// 128-VGPR/thread budget (WRITE_SIZE 0.38->2.15GB = scratch spills). Fix: shrink the
// prefetch unit so depth fits registers.
//  - L1 = FOUR single-gate passes (i,f,g,o): per k-step 2 frags -> depth-3 rotation
//    is 24 VGPRs (was 64); acc 16 (was 32). Cell math split across epilogues.
//    Side effect: instantaneous weight window/pass = 1.1MB (was 4.5) -> better
//    per-XCD L2 sharing across the 32 co-resident WGs.
//  - L2/L3 = two 2-gate passes, depth-2 ping-pong of 4-frag sets (32 VGPRs max).
//  - Bias added in epilogue (acc zero-init) - no bias-load stall at pass entry.
//  - Keep: LDS-only barriers (no vmcnt drain), entry hoists (<=24 regs across any
//    barrier), x staging split load-early/write-late, backedge L1 entry prefetch.
__global__ __launch_bounds__(1024, 4) void lstm3_v4(
    const float* __restrict__ x1, const float* __restrict__ x2,
    const unsigned short* __restrict__ l1w, const unsigned short* __restrict__ l2w,
    const unsigned short* __restrict__ l3w,
    const float* __restrict__ b1, const float* __restrict__ b2, const float* __restrict__ b3,
    float* __restrict__ dbuf)
{
    extern __shared__ unsigned short sm[];
    unsigned short* h1hi = sm;                    // [32][520]
    unsigned short* h1lo = h1hi + 32 * 520;
    unsigned short* h2hi = h1lo + 32 * 520;       // [2][32][136]
    unsigned short* h2lo = h2hi + 2 * 32 * 136;
    unsigned short* h3hi = h2lo + 2 * 32 * 136;   // [2][32][72]
    unsigned short* h3lo = h3hi + 2 * 32 * 72;
    unsigned short* xhi  = h3lo + 2 * 32 * 72;    // [2][32][72] double-buffered
    unsigned short* xlo  = xhi  + 2 * 32 * 72;

    const int tid  = threadIdx.x;
    const int wv   = tid >> 6;
    const int lane = tid & 63;
    const int wg   = blockIdx.x;
    const int samp0 = wg * 16;

    {
        unsigned int* p = (unsigned int*)sm;
        for (int i = tid; i < 29952; i += 1024) p[i] = 0u;
    }

    // L1 lane mapping (32x32)
    const int n1 = lane & 31;
    const int kh = lane >> 5;
    const int u1 = wv * 32 + n1;
    // L2/L3 lane mapping (16x16)
    const int n2   = lane & 15;
    const int quad = lane >> 4;
    const int mt2  = wv >> 3, cg2 = wv & 7;
    const int u2   = cg2 * 16 + n2;
    const int row2 = mt2 * 16 + n2;
    const int mt3  = (wv >> 2) & 1, cg3 = wv & 3;
    const int u3   = cg3 * 16 + n2;
    const int row3 = mt3 * 16 + n2;

    float c1[16], c2[4], c3[4];
    #pragma unroll
    for (int r = 0; r < 16; ++r) c1[r] = 0.0f;
    #pragma unroll
    for (int r = 0; r < 4; ++r) { c2[r] = 0.0f; c3[r] = 0.0f; }

    const unsigned short* B1p = l1w + wv * 4096 + lane * 8;
    const unsigned short* B2p = l2w + cg2 * 4096 + lane * 8;
    const unsigned short* B3p = l3w + cg3 * 4096 + lane * 8;

    // register pools (rotation sets; liveness is per-range, reused across passes)
    short8 w0h, w0l, w1h, w1l, w2h, w2l;                 // L1 pool (24 VGPR)
    short8 qa0, qa1, qa2, qa3, qb0, qb1, qb2, qb3;       // L2 pool (32 VGPR)
    short8 ra0, ra1, ra2, ra3, rb0, rb1, rb2, rb3;       // L3 pool (32 VGPR)

    // t=0 pass_i entry prefetch (rev=false, gate offset 0)
    L1_ENTRY(0, false);

    // stage x_0 into parity-0 buffer (prologue)
    for (int e = tid; e < 2048; e += 1024) {
        int b = e >> 6, f = e & 63;
        const float* __restrict__ xp = (b < 16) ? x1 : x2;
        float v = (f < 58) ? xp[(samp0 + (b & 15)) * 1740 + f * 30 + 0] : 0.0f;
        unsigned short hi = f2b(v);
        xhi[b * 72 + f] = hi;
        xlo[b * 72 + f] = f2b(v - b2f(hi));
    }
    bar_lds();

    int cur = 0;
    #pragma unroll 1
    for (int t = 0; t < NTIME; ++t) {
        const bool rev = (t & 1);
        const int nxt = cur ^ 1;
        const unsigned short* xh = xhi + (t & 1) * 2304;
        const unsigned short* xl = xlo + (t & 1) * 2304;

        float i1[16];   // sigmoid(i-gate), carried pass_i -> pass_g

        // ===== L1 pass i =====
        {
            f32x16 P;
            #pragma unroll
            for (int r = 0; r < 16; ++r) P[r] = 0.0f;
            float bg = b1[u1];
            L1_KLOOP(0);
            L1_ENTRY(1024, rev);      // pass_f entry, hides under epilogue
            #pragma unroll
            for (int r = 0; r < 16; ++r) i1[r] = sigf(P[r] + bg);
        }
        // ===== L1 pass f =====
        {
            f32x16 P;
            #pragma unroll
            for (int r = 0; r < 16; ++r) P[r] = 0.0f;
            float bg = b1[512 + u1];
            L1_KLOOP(1024);
            L1_ENTRY(2048, rev);      // pass_g entry
            #pragma unroll
            for (int r = 0; r < 16; ++r) c1[r] *= sigf(P[r] + bg);
        }
        // ===== L1 pass g =====
        {
            f32x16 P;
            #pragma unroll
            for (int r = 0; r < 16; ++r) P[r] = 0.0f;
            float bg = b1[1024 + u1];
            L1_KLOOP(2048);
            L1_ENTRY(3072, rev);      // pass_o entry
            #pragma unroll
            for (int r = 0; r < 16; ++r) c1[r] += i1[r] * tanhfast(P[r] + bg);
        }
        // ===== L1 pass o =====
        {
            f32x16 P;
            #pragma unroll
            for (int r = 0; r < 16; ++r) P[r] = 0.0f;
            float bg = b1[1536 + u1];
            L1_KLOOP(3072);
            bar_lds();   // B: all reads of h1(t-1)/x(t) done
            #pragma unroll
            for (int r = 0; r < 16; ++r) {
                float O = sigf(P[r] + bg);
                float h = O * tanhfast(c1[r]);
                int row = (r & 3) + 8 * (r >> 2) + 4 * kh;   // verified 32x32 C-map
                unsigned short hh = f2b(h);
                h1hi[row * 520 + u1] = hh;
                h1lo[row * 520 + u1] = f2b(h - b2f(hh));
            }
        }
        bar_lds();   // C: h1(t) visible

        // x(t+1): issue global loads FIRST (oldest in vmcnt queue), weights next,
        // LDS write after -> the ds_write's vmcnt wait doesn't drain weight fetches.
        float xv0, xv1;
        if (t + 1 < NTIME) {
            int b = tid >> 6, f = tid & 63;
            int idx = (samp0 + b) * 1740 + f * 30 + (t + 1);
            xv0 = (f < 58) ? x1[idx] : 0.0f;
            xv1 = (f < 58) ? x2[idx] : 0.0f;
        }

        L2_ENTRY(0);   // L2 pass0 entry (overlaps x conversion + write)

        if (t + 1 < NTIME) {
            unsigned short* xh2 = xhi + ((t + 1) & 1) * 2304;
            unsigned short* xl2 = xlo + ((t + 1) & 1) * 2304;
            int b = tid >> 6, f = tid & 63;
            unsigned short h0 = f2b(xv0);
            xh2[b * 72 + f] = h0;
            xl2[b * 72 + f] = f2b(xv0 - b2f(h0));
            unsigned short h1_ = f2b(xv1);
            xh2[(16 + b) * 72 + f] = h1_;
            xl2[(16 + b) * 72 + f] = f2b(xv1 - b2f(h1_));
        }

        float I2[4];   // carried L2 pass0 -> pass1

        // ===== L2 pass 0: gates i,f; k = [relu(h1) 512 | h2 128], 20 ksteps =====
        {
            f32x4 A0 = {0.0f, 0.0f, 0.0f, 0.0f};
            f32x4 A1 = {0.0f, 0.0f, 0.0f, 0.0f};
            float bg0 = b2[u2], bg1 = b2[128 + u2];
            #pragma unroll 1
            for (int ss = 0; ss < 20; ss += 2) {
                L2_SUB(qa0, qa1, qa2, qa3, 0, 0);
                L2_SUB(qb0, qb1, qb2, qb3, 1, 0);
            }
            L2_ENTRY(2048);   // pass1 entry, hides under epilogue
            #pragma unroll
            for (int r = 0; r < 4; ++r) {
                I2[r] = sigf(A0[r] + bg0);
                c2[r] *= sigf(A1[r] + bg1);
            }
        }
        // ===== L2 pass 1: gates g,o =====
        {
            f32x4 A0 = {0.0f, 0.0f, 0.0f, 0.0f};
            f32x4 A1 = {0.0f, 0.0f, 0.0f, 0.0f};
            float bg0 = b2[256 + u2], bg1 = b2[384 + u2];
            #pragma unroll 1
            for (int ss = 0; ss < 20; ss += 2) {
                L2_SUB(qa0, qa1, qa2, qa3, 0, 2048);
                L2_SUB(qb0, qb1, qb2, qb3, 1, 2048);
            }
            if (wv < 8) L3_ENTRY_A(0);   // L3 pass0 first set, lives across bar D (16 regs)
            #pragma unroll
            for (int r = 0; r < 4; ++r) {
                float G = tanhfast(A0[r] + bg0);
                float O = sigf(A1[r] + bg1);
                float c = c2[r] + I2[r] * G;
                c2[r] = c;
                float h = O * tanhfast(c);
                int row = mt2 * 16 + quad * 4 + r;
                unsigned short hh = f2b(h);
                h2hi[nxt * 4352 + row * 136 + u2] = hh;
                h2lo[nxt * 4352 + row * 136 + u2] = f2b(h - b2f(hh));
            }
        }
        bar_lds();   // D: h2(t) + x(t+1) visible

        // ===== L3: k = [relu(h2) 128 | h3 64], 6 ksteps, waves 0-7, 2 passes =====
        if (wv < 8) {
            float I3[4];
            {
                f32x4 A0 = {0.0f, 0.0f, 0.0f, 0.0f};
                f32x4 A1 = {0.0f, 0.0f, 0.0f, 0.0f};
                float bg0 = b3[u3], bg1 = b3[64 + u3];
                L3_ENTRY_B(0);
                #pragma unroll 1
                for (int ss = 0; ss < 6; ss += 2) {
                    L3_SUB(ra0, ra1, ra2, ra3, 0, 0);
                    L3_SUB(rb0, rb1, rb2, rb3, 1, 0);
                }
                L3_ENTRY_A(2048);
                L3_ENTRY_B(2048);
                #pragma unroll
                for (int r = 0; r < 4; ++r) {
                    I3[r] = sigf(A0[r] + bg0);
                    c3[r] *= sigf(A1[r] + bg1);
                }
            }
            {
                f32x4 A0 = {0.0f, 0.0f, 0.0f, 0.0f};
                f32x4 A1 = {0.0f, 0.0f, 0.0f, 0.0f};
                float bg0 = b3[128 + u3], bg1 = b3[192 + u3];
                #pragma unroll 1
                for (int ss = 0; ss < 6; ss += 2) {
                    L3_SUB(ra0, ra1, ra2, ra3, 0, 2048);
                    L3_SUB(rb0, rb1, rb2, rb3, 1, 2048);
                }
                #pragma unroll
                for (int r = 0; r < 4; ++r) {
                    float G = tanhfast(A0[r] + bg0);
                    float O = sigf(A1[r] + bg1);
                    float c = c3[r] + I3[r] * G;
                    c3[r] = c;
                    float h = O * tanhfast(c);
                    int row = mt3 * 16 + quad * 4 + r;
                    unsigned short hh = f2b(h);
                    h3hi[nxt * 2304 + row * 72 + u3] = hh;
                    h3lo[nxt * 2304 + row * 72 + u3] = f2b(h - b2f(hh));
                }
            }
        }

        // next-t pass_i entry prefetch: L1 pool is free (last used in pass_o loop);
        // issued before bar E + d-write, survives the backedge (barriers keep vmcnt).
        if (t + 1 < NTIME) {
            L1_ENTRY(0, !rev);
        }
        bar_lds();   // E: h3(t) visible

        // d = |relu(h3_x1) - relu(h3_x2)| -> global
        {
            int b = tid >> 6, u = tid & 63;
            float ha = b2f(h3hi[nxt * 2304 + b * 72 + u]) + b2f(h3lo[nxt * 2304 + b * 72 + u]);
            float hb = b2f(h3hi[nxt * 2304 + (16 + b) * 72 + u]) + b2f(h3lo[nxt * 2304 + (16 + b) * 72 + u]);
            dbuf[(size_t)(samp0 + b) * 1920 + t * 64 + u] = fabsf(fmaxf(ha, 0.0f) - fmaxf(hb, 0.0f));
        }
        cur = nxt;
    }
}

// ---- FC head v2
__global__ __launch_bounds__(512) void head_v2(
    const float* __restrict__ dg,
    const float4* __restrict__ WT1, const float* __restrict__ bf1,
    const float4* __restrict__ WT2, const float* __restrict__ bf2,
    const float* __restrict__ Wf3, const float* __restrict__ bf3,
    const float* __restrict__ Wf4, const float* __restrict__ bf4,
    float* __restrict__ out)
{
    extern __shared__ float hds[];
    float* ds = hds;                  // [16][1928] during fc1
    float* a1 = hds;                  // [16][1032] overlay after fc1
    float* a2 = a1 + 16 * 1032;       // [16][520]
    float* a3 = a2 + 16 * 520;        // [16][16]

    const int tid = threadIdx.x;
    const int samp0 = blockIdx.x * 16;

    for (int e = tid; e < 16 * 480; e += 512) {
        int b = e / 480, jc = e - b * 480;
        const float* src = dg + (size_t)(samp0 + b) * 1920 + jc * 4;
        float* dst = ds + b * 1928 + jc * 4;
        dst[0] = src[0]; dst[1] = src[1]; dst[2] = src[2]; dst[3] = src[3];
    }
    __syncthreads();

    const int w = tid >> 6, lane = tid & 63;
    const int oA = w * 128 + lane, oB = oA + 64;
    float accA[16], accB[16];
    {
        float bA = (oA < 960) ? bf1[oA] : 0.0f;
        float bB = (oB < 960) ? bf1[oB] : 0.0f;
        #pragma unroll
        for (int r = 0; r < 16; ++r) { accA[r] = bA; accB[r] = bB; }
    }
    #pragma unroll 2
    for (int kc = 0; kc < 480; ++kc) {
        float4 wA = WT1[kc * 1024 + oA];
        float4 wB = WT1[kc * 1024 + oB];
        #pragma unroll
        for (int r = 0; r < 16; ++r) {
            float4 d4 = ((const float4*)(ds + r * 1928))[kc];
            accA[r] += d4.x * wA.x + d4.y * wA.y + d4.z * wA.z + d4.w * wA.w;
            accB[r] += d4.x * wB.x + d4.y * wB.y + d4.z * wB.z + d4.w * wB.w;
        }
    }
    __syncthreads();
    #pragma unroll
    for (int r = 0; r < 16; ++r) {
        a1[r * 1032 + oA] = fmaxf(accA[r], 0.0f);
        a1[r * 1032 + oB] = fmaxf(accB[r], 0.0f);
    }
    __syncthreads();

    const int o2 = tid;
    float acc2[16];
    {
        float b = (o2 < 480) ? bf2[o2] : 0.0f;
        #pragma unroll
        for (int r = 0; r < 16; ++r) acc2[r] = b;
    }
    #pragma unroll 2
    for (int kc = 0; kc < 256; ++kc) {
        float4 w4 = WT2[kc * 512 + o2];
        #pragma unroll
        for (int r = 0; r < 16; ++r) {
            float4 a4 = ((const float4*)(a1 + r * 1032))[kc];
            acc2[r] += a4.x * w4.x + a4.y * w4.y + a4.z * w4.z + a4.w * w4.w;
        }
    }
    #pragma unroll
    for (int r = 0; r < 16; ++r) a2[r * 520 + o2] = fmaxf(acc2[r], 0.0f);
    __syncthreads();

    if (tid < 256) {
        int o = tid & 15, r = tid >> 4;
        float acc = bf3[o];
        const float4* wr = (const float4*)(Wf3 + (size_t)o * 480);
        const float4* av = (const float4*)(a2 + r * 520);
        #pragma unroll 4
        for (int kc = 0; kc < 120; ++kc) {
            float4 a4 = av[kc];
            float4 w4 = wr[kc];
            acc += a4.x * w4.x + a4.y * w4.y + a4.z * w4.z + a4.w * w4.w;
        }
        a3[r * 16 + o] = fmaxf(acc, 0.0f);
    }
    __syncthreads();

    if (tid < 16) {
        float acc = bf4[0];
        #pragma unroll
        for (int k = 0; k < 16; ++k) acc += a3[tid * 16 + k] * Wf4[k];
        out[samp0 + tid] = acc;
    }
}

extern "C" void kernel_launch(void* const* d_in, const int* in_sizes, int n_in,
                              void* d_out, int out_size, void* d_ws, size_t ws_size,
                              hipStream_t stream) {
    const float* x1   = (const float*)d_in[0];
    const float* x2   = (const float*)d_in[1];
    const float* Wih1 = (const float*)d_in[2];
    const float* Whh1 = (const float*)d_in[3];
    const float* b1   = (const float*)d_in[4];
    const float* Wih2 = (const float*)d_in[5];
    const float* Whh2 = (const float*)d_in[6];
    const float* b2   = (const float*)d_in[7];
    const float* Wih3 = (const float*)d_in[8];
    const float* Whh3 = (const float*)d_in[9];
    const float* b3   = (const float*)d_in[10];
    const float* Wf1  = (const float*)d_in[11];
    const float* bf1  = (const float*)d_in[12];
    const float* Wf2  = (const float*)d_in[13];
    const float* bf2  = (const float*)d_in[14];
    const float* Wf3  = (const float*)d_in[15];
    const float* bf3  = (const float*)d_in[16];
    const float* Wf4  = (const float*)d_in[17];
    const float* bf4  = (const float*)d_in[18];

    float* wsf = (float*)d_ws;
    float* dbuf = wsf;                                         // 4096*1920 = 7,864,320 f32
    unsigned short* l1w = (unsigned short*)(wsf + 7864320);    // 36*65536  = 2,359,296 us
    unsigned short* l2w = l1w + 2359296;                       // 20*8*4096 =   655,360 us
    unsigned short* l3w = l2w + 655360;                        //  6*4*4096 =    98,304 us
    float4* WT1 = (float4*)(wsf + 9420800);                    // 480*1024 float4
    float4* WT2 = WT1 + 480 * 1024;                            // 256*512  float4
    float* out = (float*)d_out;

    prep_w32<<<(36 * 65536) / 256, 256, 0, stream>>>(Wih1, Whh1, l1w);
    prep_w16<<<(20 * 8 * 4096) / 256, 256, 0, stream>>>(Wih2, Whh2, l2w, 128, 512, 512, 128, 8, 20);
    prep_w16<<<(6 * 4 * 4096) / 256, 256, 0, stream>>>(Wih3, Whh3, l3w, 64, 128, 128, 64, 4, 6);
    pack_wt1<<<(480 * 1024) / 256, 256, 0, stream>>>(Wf1, WT1);
    pack_wt2<<<(256 * 512) / 256, 256, 0, stream>>>(Wf2, WT2);

    (void)hipFuncSetAttribute((const void*)lstm3_v4,
                              hipFuncAttributeMaxDynamicSharedMemorySize, 138240);
    lstm3_v4<<<256, 1024, 138240, stream>>>(x1, x2, l1w, l2w, l3w, b1, b2, b3, dbuf);

    (void)hipFuncSetAttribute((const void*)head_v2,
                              hipFuncAttributeMaxDynamicSharedMemorySize, 16 * 1928 * 4);
    head_v2<<<256, 512, 16 * 1928 * 4, stream>>>(dbuf, WT1, bf1, WT2, bf2,
                                                 Wf3, bf3, Wf4, bf4, out);
}

// Round 3
// 3219.096 us; speedup vs baseline: 1.3501x; 1.3246x over previous
//
#include <hip/hip_runtime.h>

#define NTIME 30
#define NB 4096

typedef __attribute__((ext_vector_type(8))) short short8;
typedef __attribute__((ext_vector_type(4))) float f32x4;
typedef __attribute__((ext_vector_type(16))) float f32x16;

__device__ __forceinline__ unsigned short f2b(float f) {
    unsigned int u = __float_as_uint(f);
    u = u + 0x7FFFu + ((u >> 16) & 1u);        // RNE to bf16
    return (unsigned short)(u >> 16);
}
__device__ __forceinline__ float b2f(unsigned short s) {
    return __uint_as_float(((unsigned int)s) << 16);
}
__device__ __forceinline__ float sigf(float x)     { return 1.0f / (1.0f + __expf(-x)); }
__device__ __forceinline__ float tanhfast(float x) { return 1.0f - 2.0f / (__expf(2.0f * x) + 1.0f); }

// LDS-only barrier: all cross-wave communication inside lstm3 is via LDS, so we
// only need lgkmcnt(0)+s_barrier. Does NOT drain vmcnt -> global weight
// prefetches stay in flight across phase boundaries.
__device__ __forceinline__ void bar_lds() {
    asm volatile("s_waitcnt lgkmcnt(0)" ::: "memory");
    __builtin_amdgcn_s_barrier();
    asm volatile("" ::: "memory");
}

// ---- L1 weight pack: 32x32x16 B-frags, SINGLE bf16 plane (round-12).
// Layout: [s(36)][w(16)][g(4)][lane(64)][j(8)] -> wave slice stride 2048,
// kstep slab stride 32768, gate stride 512.
__global__ __launch_bounds__(256) void prep_w32s(const float* __restrict__ Wih,
                                                 const float* __restrict__ Whh,
                                                 unsigned short* __restrict__ out)
{
    int e = blockIdx.x * 256 + threadIdx.x;
    if (e >= 36 * 32768) return;
    int j    = e & 7;
    int lane = (e >> 3) & 63;
    int g    = (e >> 9) & 3;
    int w    = (e >> 11) & 15;
    int s    = e >> 15;
    int n = lane & 31, kh = lane >> 5;
    int unit = w * 32 + n;
    int k = s * 16 + kh * 8 + j;
    int row = g * 512 + unit;
    float v = 0.0f;
    if (k < 64) { if (k < 58) v = Wih[row * 58 + k]; }
    else        { v = Whh[row * 512 + (k - 64)]; }
    out[e] = f2b(v);
}

// ---- L2/L3 weight pack: 16x16x32 B-frags, single plane.
// Layout: [s][cg(CG)][g(4)][lane(64)][j(8)] -> cg stride 2048, slab CG*2048.
__global__ __launch_bounds__(256) void prep_w16s(const float* __restrict__ Wih,
                                                 const float* __restrict__ Whh,
                                                 unsigned short* __restrict__ out,
                                                 int H, int KI, int KIp, int KH, int CG, int KS)
{
    int e = blockIdx.x * 256 + threadIdx.x;
    if (e >= KS * CG * 2048) return;
    int j    = e & 7;
    int lane = (e >> 3) & 63;
    int g    = (e >> 9) & 3;
    int rest = e >> 11;
    int cg = rest % CG;
    int s  = rest / CG;
    int n = lane & 15, q = lane >> 4;
    int unit = cg * 16 + n;
    int k = s * 32 + q * 8 + j;
    int row = g * H + unit;
    float v = 0.0f;
    if (k < KIp) { if (k < KI) v = Wih[row * KI + k]; }
    else         { v = Whh[row * KH + (k - KIp)]; }
    out[e] = f2b(v);
}

// ---- Head weight transposes (o-fastest float4 blocks)
__global__ __launch_bounds__(256) void pack_wt1(const float* __restrict__ Wf1, float4* __restrict__ WT1)
{
    int e = blockIdx.x * 256 + threadIdx.x;
    if (e >= 480 * 1024) return;
    int kc = e >> 10, o = e & 1023;
    float4 v = {0.0f, 0.0f, 0.0f, 0.0f};
    if (o < 960) {
        const float* p = Wf1 + (size_t)o * 1920 + kc * 4;
        v.x = p[0]; v.y = p[1]; v.z = p[2]; v.w = p[3];
    }
    WT1[e] = v;
}
__global__ __launch_bounds__(256) void pack_wt2(const float* __restrict__ Wf2, float4* __restrict__ WT2)
{
    int e = blockIdx.x * 256 + threadIdx.x;
    if (e >= 256 * 512) return;
    int kc = e >> 9, o = e & 511;
    float4 v = {0.0f, 0.0f, 0.0f, 0.0f};
    if (o < 480) {
        int k = kc * 4;
        v.x = (k + 0 < 960) ? Wf2[(size_t)o * 960 + k + 0] : 0.0f;
        v.y = (k + 1 < 960) ? Wf2[(size_t)o * 960 + k + 1] : 0.0f;
        v.z = (k + 2 < 960) ? Wf2[(size_t)o * 960 + k + 2] : 0.0f;
        v.w = (k + 3 < 960) ? Wf2[(size_t)o * 960 + k + 3] : 0.0f;
    }
    WT2[e] = v;
}

#define MFMA32(A, X, B) A = __builtin_amdgcn_mfma_f32_32x32x16_bf16((X), (B), (A), 0, 0, 0)
#define MFMA16(A, X, B) A = __builtin_amdgcn_mfma_f32_16x16x32_bf16((X), (B), (A), 0, 0, 0)

// L1 A-fragment load (x for s<4, h1 otherwise); activations stay hi/lo.
#define L1_LOAD_A(SV) do { \
    if ((SV) < 4) { \
        const int _off = (SV) * 16 + kh * 8; \
        ahi = *(const short8*)(xh + n1 * 72 + _off); \
        alo = *(const short8*)(xl + n1 * 72 + _off); \
    } else { \
        const int _off = ((SV) - 4) * 16 + kh * 8; \
        ahi = *(const short8*)(h1hi + n1 * 520 + _off); \
        alo = *(const short8*)(h1lo + n1 * 520 + _off); \
    } } while (0)

// one L1 k-step of a 2-gate pass: 4 MFMAs (ahi,alo x gateA,gateB), then refill
// the just-freed weight set with the step 3 ahead (depth-3 rotation).
#define L1_SUB(WA, WB, IDX, GOFF) do { \
    const int _s = rev ? (35 - (ss + (IDX))) : (ss + (IDX)); \
    short8 ahi, alo; \
    L1_LOAD_A(_s); \
    MFMA32(P0, ahi, WA); \
    MFMA32(P1, ahi, WB); \
    MFMA32(P0, alo, WA); \
    MFMA32(P1, alo, WB); \
    if (ss + (IDX) + 3 < 36) { \
        const int _sn = rev ? (35 - (ss + (IDX) + 3)) : (ss + (IDX) + 3); \
        const unsigned short* _bb = B1p + _sn * 32768 + (GOFF); \
        WA = *(const short8*)(_bb); \
        WB = *(const short8*)(_bb + 512); \
    } } while (0)

#define L1_KLOOP(GOFF) \
    _Pragma("unroll 1") \
    for (int ss = 0; ss < 36; ss += 3) { \
        L1_SUB(w0a, w0b, 0, GOFF); \
        L1_SUB(w1a, w1b, 1, GOFF); \
        L1_SUB(w2a, w2b, 2, GOFF); \
    }

// entry prefetch of the first 3 k-steps of a pass. RV = direction of that pass.
#define L1_ENTRY(GOFF, RV) do { \
    const int _s0 = (RV) ? 35 : 0, _s1 = (RV) ? 34 : 1, _s2 = (RV) ? 33 : 2; \
    const unsigned short* _b0 = B1p + _s0 * 32768 + (GOFF); \
    const unsigned short* _b1 = B1p + _s1 * 32768 + (GOFF); \
    const unsigned short* _b2 = B1p + _s2 * 32768 + (GOFF); \
    w0a = *(const short8*)(_b0); w0b = *(const short8*)(_b0 + 512); \
    w1a = *(const short8*)(_b1); w1b = *(const short8*)(_b1 + 512); \
    w2a = *(const short8*)(_b2); w2b = *(const short8*)(_b2 + 512); \
} while (0)

#define L2_LOAD_A(SV) do { \
    if ((SV) < 16) { \
        const int _off = (SV) * 32 + quad * 8; \
        short8 _a  = *(const short8*)(h1hi + row2 * 520 + _off); \
        short8 _al = *(const short8*)(h1lo + row2 * 520 + _off); \
        short8 _msk = _a >> 15; \
        ahi = _a & ~_msk; alo = _al & ~_msk; \
    } else { \
        const int _off = ((SV) - 16) * 32 + quad * 8; \
        ahi = *(const short8*)(h2hi + cur * 4352 + row2 * 136 + _off); \
        alo = *(const short8*)(h2lo + cur * 4352 + row2 * 136 + _off); \
    } } while (0)

// one L2 k-step, all 4 gates single-plane: 8 MFMAs, depth-2 ping-pong refill.
#define L2_SUB(Q0, Q1, Q2, Q3, IDX) do { \
    const int _s = rev ? (19 - (ss + (IDX))) : (ss + (IDX)); \
    short8 ahi, alo; \
    L2_LOAD_A(_s); \
    MFMA16(A0, ahi, Q0); \
    MFMA16(A1, ahi, Q1); \
    MFMA16(A2, ahi, Q2); \
    MFMA16(A3, ahi, Q3); \
    MFMA16(A0, alo, Q0); \
    MFMA16(A1, alo, Q1); \
    MFMA16(A2, alo, Q2); \
    MFMA16(A3, alo, Q3); \
    if (ss + (IDX) + 2 < 20) { \
        const int _sn = rev ? (19 - (ss + (IDX) + 2)) : (ss + (IDX) + 2); \
        const unsigned short* _bb = B2p + _sn * 16384; \
        Q0 = *(const short8*)(_bb); \
        Q1 = *(const short8*)(_bb + 512); \
        Q2 = *(const short8*)(_bb + 1024); \
        Q3 = *(const short8*)(_bb + 1536); \
    } } while (0)

#define L2_ENTRY() do { \
    const int _s0 = rev ? 19 : 0, _s1 = rev ? 18 : 1; \
    const unsigned short* _b0 = B2p + _s0 * 16384; \
    const unsigned short* _b1 = B2p + _s1 * 16384; \
    qa0 = *(const short8*)(_b0);        qa1 = *(const short8*)(_b0 + 512); \
    qa2 = *(const short8*)(_b0 + 1024); qa3 = *(const short8*)(_b0 + 1536); \
    qb0 = *(const short8*)(_b1);        qb1 = *(const short8*)(_b1 + 512); \
    qb2 = *(const short8*)(_b1 + 1024); qb3 = *(const short8*)(_b1 + 1536); \
} while (0)

#define L3_LOAD_A(SV) do { \
    if ((SV) < 4) { \
        const int _off = (SV) * 32 + quad * 8; \
        short8 _a  = *(const short8*)(h2hi + nxt * 4352 + row3 * 136 + _off); \
        short8 _al = *(const short8*)(h2lo + nxt * 4352 + row3 * 136 + _off); \
        short8 _msk = _a >> 15; \
        ahi = _a & ~_msk; alo = _al & ~_msk; \
    } else { \
        const int _off = ((SV) - 4) * 32 + quad * 8; \
        ahi = *(const short8*)(h3hi + cur * 2304 + row3 * 72 + _off); \
        alo = *(const short8*)(h3lo + cur * 2304 + row3 * 72 + _off); \
    } } while (0)

#define L3_SUB(Q0, Q1, Q2, Q3, IDX) do { \
    const int _s = rev ? (5 - (ss + (IDX))) : (ss + (IDX)); \
    short8 ahi, alo; \
    L3_LOAD_A(_s); \
    MFMA16(A0, ahi, Q0); \
    MFMA16(A1, ahi, Q1); \
    MFMA16(A2, ahi, Q2); \
    MFMA16(A3, ahi, Q3); \
    MFMA16(A0, alo, Q0); \
    MFMA16(A1, alo, Q1); \
    MFMA16(A2, alo, Q2); \
    MFMA16(A3, alo, Q3); \
    if (ss + (IDX) + 2 < 6) { \
        const int _sn = rev ? (5 - (ss + (IDX) + 2)) : (ss + (IDX) + 2); \
        const unsigned short* _bb = B3p + _sn * 8192; \
        Q0 = *(const short8*)(_bb); \
        Q1 = *(const short8*)(_bb + 512); \
        Q2 = *(const short8*)(_bb + 1024); \
        Q3 = *(const short8*)(_bb + 1536); \
    } } while (0)

#define L3_ENTRY_A() do { \
    const int _s0 = rev ? 5 : 0; \
    const unsigned short* _b0 = B3p + _s0 * 8192; \
    ra0 = *(const short8*)(_b0);        ra1 = *(const short8*)(_b0 + 512); \
    ra2 = *(const short8*)(_b0 + 1024); ra3 = *(const short8*)(_b0 + 1536); \
} while (0)

#define L3_ENTRY_B() do { \
    const int _s1 = rev ? 4 : 1; \
    const unsigned short* _b1 = B3p + _s1 * 8192; \
    rb0 = *(const short8*)(_b1);        rb1 = *(const short8*)(_b1 + 512); \
    rb2 = *(const short8*)(_b1 + 1024); rb3 = *(const short8*)(_b1 + 1536); \
} while (0)

// ---- Fused Siamese 3-layer LSTM. 256 WGs x 1024 thr (16 waves, 4/SIMD), 135KB LDS.
// Round-12 (v5): SINGLE-PLANE bf16 weights (activations keep hi/lo split).
//  - weight stream halves: 45.6 -> 22.8 GB; MFMA count x2/3 (2 per gate-kstep).
//  - L1: two 2-gate passes, depth-3 rotating prefetch (24 VGPR).
//  - L2/L3: single 4-gate pass (A-LDS reads halve vs 2-pass), depth-2 ping-pong.
//  - LDS-only barriers (vmcnt survives phases), entry hoists, backedge prefetch,
//    split x staging. Everything fits ~110 VGPR -> no scratch (watch WRITE_SIZE).
__global__ __launch_bounds__(1024, 4) void lstm3_v5(
    const float* __restrict__ x1, const float* __restrict__ x2,
    const unsigned short* __restrict__ l1w, const unsigned short* __restrict__ l2w,
    const unsigned short* __restrict__ l3w,
    const float* __restrict__ b1, const float* __restrict__ b2, const float* __restrict__ b3,
    float* __restrict__ dbuf)
{
    extern __shared__ unsigned short sm[];
    unsigned short* h1hi = sm;                    // [32][520]
    unsigned short* h1lo = h1hi + 32 * 520;
    unsigned short* h2hi = h1lo + 32 * 520;       // [2][32][136]
    unsigned short* h2lo = h2hi + 2 * 32 * 136;
    unsigned short* h3hi = h2lo + 2 * 32 * 136;   // [2][32][72]
    unsigned short* h3lo = h3hi + 2 * 32 * 72;
    unsigned short* xhi  = h3lo + 2 * 32 * 72;    // [2][32][72] double-buffered
    unsigned short* xlo  = xhi  + 2 * 32 * 72;

    const int tid  = threadIdx.x;
    const int wv   = tid >> 6;
    const int lane = tid & 63;
    const int wg   = blockIdx.x;
    const int samp0 = wg * 16;

    {
        unsigned int* p = (unsigned int*)sm;
        for (int i = tid; i < 29952; i += 1024) p[i] = 0u;
    }

    // L1 lane mapping (32x32)
    const int n1 = lane & 31;
    const int kh = lane >> 5;
    const int u1 = wv * 32 + n1;
    // L2/L3 lane mapping (16x16)
    const int n2   = lane & 15;
    const int quad = lane >> 4;
    const int mt2  = wv >> 3, cg2 = wv & 7;
    const int u2   = cg2 * 16 + n2;
    const int row2 = mt2 * 16 + n2;
    const int mt3  = (wv >> 2) & 1, cg3 = wv & 3;
    const int u3   = cg3 * 16 + n2;
    const int row3 = mt3 * 16 + n2;

    float c1[16], c2[4], c3[4];
    #pragma unroll
    for (int r = 0; r < 16; ++r) c1[r] = 0.0f;
    #pragma unroll
    for (int r = 0; r < 4; ++r) { c2[r] = 0.0f; c3[r] = 0.0f; }

    const unsigned short* B1p = l1w + wv * 2048 + lane * 8;
    const unsigned short* B2p = l2w + cg2 * 2048 + lane * 8;
    const unsigned short* B3p = l3w + cg3 * 2048 + lane * 8;

    // register pools
    short8 w0a, w0b, w1a, w1b, w2a, w2b;             // L1 rotation (24 VGPR)
    short8 qa0, qa1, qa2, qa3, qb0, qb1, qb2, qb3;   // L2 ping-pong (32 VGPR)
    short8 ra0, ra1, ra2, ra3, rb0, rb1, rb2, rb3;   // L3 ping-pong (32 VGPR)

    // t=0 pass0 entry prefetch (fwd direction, gates i,f)
    L1_ENTRY(0, false);

    // stage x_0 into parity-0 buffer (prologue)
    for (int e = tid; e < 2048; e += 1024) {
        int b = e >> 6, f = e & 63;
        const float* __restrict__ xp = (b < 16) ? x1 : x2;
        float v = (f < 58) ? xp[(samp0 + (b & 15)) * 1740 + f * 30 + 0] : 0.0f;
        unsigned short hi = f2b(v);
        xhi[b * 72 + f] = hi;
        xlo[b * 72 + f] = f2b(v - b2f(hi));
    }
    bar_lds();

    int cur = 0;
    #pragma unroll 1
    for (int t = 0; t < NTIME; ++t) {
        const bool rev = (t & 1);
        const int nxt = cur ^ 1;
        const unsigned short* xh = xhi + (t & 1) * 2304;
        const unsigned short* xl = xlo + (t & 1) * 2304;

        float i1[16];   // sigmoid(i-gate), carried pass0 -> pass1

        // ===== L1 pass 0: gates i,f =====
        {
            f32x16 P0, P1;
            #pragma unroll
            for (int r = 0; r < 16; ++r) { P0[r] = 0.0f; P1[r] = 0.0f; }
            float bg0 = b1[u1], bg1 = b1[512 + u1];
            L1_KLOOP(0);
            L1_ENTRY(1024, rev);      // pass1 entry (gates g,o), hides under epilogue
            #pragma unroll
            for (int r = 0; r < 16; ++r) {
                i1[r] = sigf(P0[r] + bg0);
                c1[r] *= sigf(P1[r] + bg1);
            }
        }
        // ===== L1 pass 1: gates g,o =====
        {
            f32x16 P0, P1;
            #pragma unroll
            for (int r = 0; r < 16; ++r) { P0[r] = 0.0f; P1[r] = 0.0f; }
            float bg0 = b1[1024 + u1], bg1 = b1[1536 + u1];
            L1_KLOOP(1024);
            bar_lds();   // B: all reads of h1(t-1)/x(t) done
            #pragma unroll
            for (int r = 0; r < 16; ++r) {
                float G = tanhfast(P0[r] + bg0);
                float O = sigf(P1[r] + bg1);
                float c = c1[r] + i1[r] * G;
                c1[r] = c;
                float h = O * tanhfast(c);
                int row = (r & 3) + 8 * (r >> 2) + 4 * kh;   // verified 32x32 C-map
                unsigned short hh = f2b(h);
                h1hi[row * 520 + u1] = hh;
                h1lo[row * 520 + u1] = f2b(h - b2f(hh));
            }
        }
        bar_lds();   // C: h1(t) visible

        // x(t+1): issue global loads first, then L2 weight entry, LDS writes last.
        float xv0, xv1;
        if (t + 1 < NTIME) {
            int b = tid >> 6, f = tid & 63;
            int idx = (samp0 + b) * 1740 + f * 30 + (t + 1);
            xv0 = (f < 58) ? x1[idx] : 0.0f;
            xv1 = (f < 58) ? x2[idx] : 0.0f;
        }

        L2_ENTRY();   // L2 entry frags (overlaps x conversion + write)

        if (t + 1 < NTIME) {
            unsigned short* xh2 = xhi + ((t + 1) & 1) * 2304;
            unsigned short* xl2 = xlo + ((t + 1) & 1) * 2304;
            int b = tid >> 6, f = tid & 63;
            unsigned short h0 = f2b(xv0);
            xh2[b * 72 + f] = h0;
            xl2[b * 72 + f] = f2b(xv0 - b2f(h0));
            unsigned short h1_ = f2b(xv1);
            xh2[(16 + b) * 72 + f] = h1_;
            xl2[(16 + b) * 72 + f] = f2b(xv1 - b2f(h1_));
        }

        // ===== L2: single 4-gate pass; k = [relu(h1) 512 | h2 128], 20 ksteps =====
        {
            f32x4 A0 = {0.0f, 0.0f, 0.0f, 0.0f};
            f32x4 A1 = {0.0f, 0.0f, 0.0f, 0.0f};
            f32x4 A2 = {0.0f, 0.0f, 0.0f, 0.0f};
            f32x4 A3 = {0.0f, 0.0f, 0.0f, 0.0f};
            float bg0 = b2[u2], bg1 = b2[128 + u2], bg2 = b2[256 + u2], bg3 = b2[384 + u2];
            #pragma unroll 1
            for (int ss = 0; ss < 20; ss += 2) {
                L2_SUB(qa0, qa1, qa2, qa3, 0);
                L2_SUB(qb0, qb1, qb2, qb3, 1);
            }
            if (wv < 8) { L3_ENTRY_A(); L3_ENTRY_B(); }   // L3 entry across bar D
            #pragma unroll
            for (int r = 0; r < 4; ++r) {
                float I = sigf(A0[r] + bg0);
                float F = sigf(A1[r] + bg1);
                float G = tanhfast(A2[r] + bg2);
                float O = sigf(A3[r] + bg3);
                float c = F * c2[r] + I * G;
                c2[r] = c;
                float h = O * tanhfast(c);
                int row = mt2 * 16 + quad * 4 + r;
                unsigned short hh = f2b(h);
                h2hi[nxt * 4352 + row * 136 + u2] = hh;
                h2lo[nxt * 4352 + row * 136 + u2] = f2b(h - b2f(hh));
            }
        }
        bar_lds();   // D: h2(t) + x(t+1) visible

        // ===== L3: single 4-gate pass; k = [relu(h2) 128 | h3 64], 6 ksteps, waves 0-7 =====
        if (wv < 8) {
            f32x4 A0 = {0.0f, 0.0f, 0.0f, 0.0f};
            f32x4 A1 = {0.0f, 0.0f, 0.0f, 0.0f};
            f32x4 A2 = {0.0f, 0.0f, 0.0f, 0.0f};
            f32x4 A3 = {0.0f, 0.0f, 0.0f, 0.0f};
            float bg0 = b3[u3], bg1 = b3[64 + u3], bg2 = b3[128 + u3], bg3 = b3[192 + u3];
            #pragma unroll 1
            for (int ss = 0; ss < 6; ss += 2) {
                L3_SUB(ra0, ra1, ra2, ra3, 0);
                L3_SUB(rb0, rb1, rb2, rb3, 1);
            }
            #pragma unroll
            for (int r = 0; r < 4; ++r) {
                float I = sigf(A0[r] + bg0);
                float F = sigf(A1[r] + bg1);
                float G = tanhfast(A2[r] + bg2);
                float O = sigf(A3[r] + bg3);
                float c = F * c3[r] + I * G;
                c3[r] = c;
                float h = O * tanhfast(c);
                int row = mt3 * 16 + quad * 4 + r;
                unsigned short hh = f2b(h);
                h3hi[nxt * 2304 + row * 72 + u3] = hh;
                h3lo[nxt * 2304 + row * 72 + u3] = f2b(h - b2f(hh));
            }
        }

        // next-t pass0 entry prefetch: issued before bar E + d-write, survives the
        // backedge (LDS-only barriers keep vmcnt).
        if (t + 1 < NTIME) {
            L1_ENTRY(0, !rev);
        }
        bar_lds();   // E: h3(t) visible

        // d = |relu(h3_x1) - relu(h3_x2)| -> global
        {
            int b = tid >> 6, u = tid & 63;
            float ha = b2f(h3hi[nxt * 2304 + b * 72 + u]) + b2f(h3lo[nxt * 2304 + b * 72 + u]);
            float hb = b2f(h3hi[nxt * 2304 + (16 + b) * 72 + u]) + b2f(h3lo[nxt * 2304 + (16 + b) * 72 + u]);
            dbuf[(size_t)(samp0 + b) * 1920 + t * 64 + u] = fabsf(fmaxf(ha, 0.0f) - fmaxf(hb, 0.0f));
        }
        cur = nxt;
    }
}

// ---- FC head v2
__global__ __launch_bounds__(512) void head_v2(
    const float* __restrict__ dg,
    const float4* __restrict__ WT1, const float* __restrict__ bf1,
    const float4* __restrict__ WT2, const float* __restrict__ bf2,
    const float* __restrict__ Wf3, const float* __restrict__ bf3,
    const float* __restrict__ Wf4, const float* __restrict__ bf4,
    float* __restrict__ out)
{
    extern __shared__ float hds[];
    float* ds = hds;                  // [16][1928] during fc1
    float* a1 = hds;                  // [16][1032] overlay after fc1
    float* a2 = a1 + 16 * 1032;       // [16][520]
    float* a3 = a2 + 16 * 520;        // [16][16]

    const int tid = threadIdx.x;
    const int samp0 = blockIdx.x * 16;

    for (int e = tid; e < 16 * 480; e += 512) {
        int b = e / 480, jc = e - b * 480;
        const float* src = dg + (size_t)(samp0 + b) * 1920 + jc * 4;
        float* dst = ds + b * 1928 + jc * 4;
        dst[0] = src[0]; dst[1] = src[1]; dst[2] = src[2]; dst[3] = src[3];
    }
    __syncthreads();

    const int w = tid >> 6, lane = tid & 63;
    const int oA = w * 128 + lane, oB = oA + 64;
    float accA[16], accB[16];
    {
        float bA = (oA < 960) ? bf1[oA] : 0.0f;
        float bB = (oB < 960) ? bf1[oB] : 0.0f;
        #pragma unroll
        for (int r = 0; r < 16; ++r) { accA[r] = bA; accB[r] = bB; }
    }
    #pragma unroll 2
    for (int kc = 0; kc < 480; ++kc) {
        float4 wA = WT1[kc * 1024 + oA];
        float4 wB = WT1[kc * 1024 + oB];
        #pragma unroll
        for (int r = 0; r < 16; ++r) {
            float4 d4 = ((const float4*)(ds + r * 1928))[kc];
            accA[r] += d4.x * wA.x + d4.y * wA.y + d4.z * wA.z + d4.w * wA.w;
            accB[r] += d4.x * wB.x + d4.y * wB.y + d4.z * wB.z + d4.w * wB.w;
        }
    }
    __syncthreads();
    #pragma unroll
    for (int r = 0; r < 16; ++r) {
        a1[r * 1032 + oA] = fmaxf(accA[r], 0.0f);
        a1[r * 1032 + oB] = fmaxf(accB[r], 0.0f);
    }
    __syncthreads();

    const int o2 = tid;
    float acc2[16];
    {
        float b = (o2 < 480) ? bf2[o2] : 0.0f;
        #pragma unroll
        for (int r = 0; r < 16; ++r) acc2[r] = b;
    }
    #pragma unroll 2
    for (int kc = 0; kc < 256; ++kc) {
        float4 w4 = WT2[kc * 512 + o2];
        #pragma unroll
        for (int r = 0; r < 16; ++r) {
            float4 a4 = ((const float4*)(a1 + r * 1032))[kc];
            acc2[r] += a4.x * w4.x + a4.y * w4.y + a4.z * w4.z + a4.w * w4.w;
        }
    }
    #pragma unroll
    for (int r = 0; r < 16; ++r) a2[r * 520 + o2] = fmaxf(acc2[r], 0.0f);
    __syncthreads();

    if (tid < 256) {
        int o = tid & 15, r = tid >> 4;
        float acc = bf3[o];
        const float4* wr = (const float4*)(Wf3 + (size_t)o * 480);
        const float4* av = (const float4*)(a2 + r * 520);
        #pragma unroll 4
        for (int kc = 0; kc < 120; ++kc) {
            float4 a4 = av[kc];
            float4 w4 = wr[kc];
            acc += a4.x * w4.x + a4.y * w4.y + a4.z * w4.z + a4.w * w4.w;
        }
        a3[r * 16 + o] = fmaxf(acc, 0.0f);
    }
    __syncthreads();

    if (tid < 16) {
        float acc = bf4[0];
        #pragma unroll
        for (int k = 0; k < 16; ++k) acc += a3[tid * 16 + k] * Wf4[k];
        out[samp0 + tid] = acc;
    }
}

extern "C" void kernel_launch(void* const* d_in, const int* in_sizes, int n_in,
                              void* d_out, int out_size, void* d_ws, size_t ws_size,
                              hipStream_t stream) {
    const float* x1   = (const float*)d_in[0];
    const float* x2   = (const float*)d_in[1];
    const float* Wih1 = (const float*)d_in[2];
    const float* Whh1 = (const float*)d_in[3];
    const float* b1   = (const float*)d_in[4];
    const float* Wih2 = (const float*)d_in[5];
    const float* Whh2 = (const float*)d_in[6];
    const float* b2   = (const float*)d_in[7];
    const float* Wih3 = (const float*)d_in[8];
    const float* Whh3 = (const float*)d_in[9];
    const float* b3   = (const float*)d_in[10];
    const float* Wf1  = (const float*)d_in[11];
    const float* bf1  = (const float*)d_in[12];
    const float* Wf2  = (const float*)d_in[13];
    const float* bf2  = (const float*)d_in[14];
    const float* Wf3  = (const float*)d_in[15];
    const float* bf3  = (const float*)d_in[16];
    const float* Wf4  = (const float*)d_in[17];
    const float* bf4  = (const float*)d_in[18];

    float* wsf = (float*)d_ws;
    float* dbuf = wsf;                                         // 4096*1920 = 7,864,320 f32
    unsigned short* l1w = (unsigned short*)(wsf + 7864320);    // 36*32768 = 1,179,648 us
    unsigned short* l2w = l1w + 1179648;                       // 20*8*2048 =  327,680 us
    unsigned short* l3w = l2w + 327680;                        //  6*4*2048 =   49,152 us
    float4* WT1 = (float4*)(wsf + 8642560);                    // 480*1024 float4
    float4* WT2 = WT1 + 480 * 1024;                            // 256*512  float4
    float* out = (float*)d_out;

    prep_w32s<<<(36 * 32768) / 256, 256, 0, stream>>>(Wih1, Whh1, l1w);
    prep_w16s<<<(20 * 8 * 2048) / 256, 256, 0, stream>>>(Wih2, Whh2, l2w, 128, 512, 512, 128, 8, 20);
    prep_w16s<<<(6 * 4 * 2048) / 256, 256, 0, stream>>>(Wih3, Whh3, l3w, 64, 128, 128, 64, 4, 6);
    pack_wt1<<<(480 * 1024) / 256, 256, 0, stream>>>(Wf1, WT1);
    pack_wt2<<<(256 * 512) / 256, 256, 0, stream>>>(Wf2, WT2);

    (void)hipFuncSetAttribute((const void*)lstm3_v5,
                              hipFuncAttributeMaxDynamicSharedMemorySize, 138240);
    lstm3_v5<<<256, 1024, 138240, stream>>>(x1, x2, l1w, l2w, l3w, b1, b2, b3, dbuf);

    (void)hipFuncSetAttribute((const void*)head_v2,
                              hipFuncAttributeMaxDynamicSharedMemorySize, 16 * 1928 * 4);
    head_v2<<<256, 512, 16 * 1928 * 4, stream>>>(dbuf, WT1, bf1, WT2, bf2,
                                                 Wf3, bf3, Wf4, bf4, out);
}

// Round 4
// 2831.797 us; speedup vs baseline: 1.5347x; 1.1368x over previous
//
#include <hip/hip_runtime.h>

#define NTIME 30
#define NB 4096

typedef __attribute__((ext_vector_type(8))) short short8;
typedef __attribute__((ext_vector_type(4))) float f32x4;
typedef __attribute__((ext_vector_type(16))) float f32x16;

__device__ __forceinline__ unsigned short f2b(float f) {
    unsigned int u = __float_as_uint(f);
    u = u + 0x7FFFu + ((u >> 16) & 1u);        // RNE to bf16
    return (unsigned short)(u >> 16);
}
__device__ __forceinline__ float b2f(unsigned short s) {
    return __uint_as_float(((unsigned int)s) << 16);
}
__device__ __forceinline__ float sigf(float x)     { return 1.0f / (1.0f + __expf(-x)); }
__device__ __forceinline__ float tanhfast(float x) { return 1.0f - 2.0f / (__expf(2.0f * x) + 1.0f); }

// LDS-only barrier: all cross-wave communication inside lstm3 is via LDS, so we
// only need lgkmcnt(0)+s_barrier. Does NOT drain vmcnt -> global weight
// prefetches stay in flight across phase boundaries.
__device__ __forceinline__ void bar_lds() {
    asm volatile("s_waitcnt lgkmcnt(0)" ::: "memory");
    __builtin_amdgcn_s_barrier();
    asm volatile("" ::: "memory");
}

// ---- L1 weight pack: 32x32x16 B-frags, SINGLE bf16 plane.
__global__ __launch_bounds__(256) void prep_w32s(const float* __restrict__ Wih,
                                                 const float* __restrict__ Whh,
                                                 unsigned short* __restrict__ out)
{
    int e = blockIdx.x * 256 + threadIdx.x;
    if (e >= 36 * 32768) return;
    int j    = e & 7;
    int lane = (e >> 3) & 63;
    int g    = (e >> 9) & 3;
    int w    = (e >> 11) & 15;
    int s    = e >> 15;
    int n = lane & 31, kh = lane >> 5;
    int unit = w * 32 + n;
    int k = s * 16 + kh * 8 + j;
    int row = g * 512 + unit;
    float v = 0.0f;
    if (k < 64) { if (k < 58) v = Wih[row * 58 + k]; }
    else        { v = Whh[row * 512 + (k - 64)]; }
    out[e] = f2b(v);
}

// ---- L2/L3 weight pack: 16x16x32 B-frags, single plane.
__global__ __launch_bounds__(256) void prep_w16s(const float* __restrict__ Wih,
                                                 const float* __restrict__ Whh,
                                                 unsigned short* __restrict__ out,
                                                 int H, int KI, int KIp, int KH, int CG, int KS)
{
    int e = blockIdx.x * 256 + threadIdx.x;
    if (e >= KS * CG * 2048) return;
    int j    = e & 7;
    int lane = (e >> 3) & 63;
    int g    = (e >> 9) & 3;
    int rest = e >> 11;
    int cg = rest % CG;
    int s  = rest / CG;
    int n = lane & 15, q = lane >> 4;
    int unit = cg * 16 + n;
    int k = s * 32 + q * 8 + j;
    int row = g * H + unit;
    float v = 0.0f;
    if (k < KIp) { if (k < KI) v = Wih[row * KI + k]; }
    else         { v = Whh[row * KH + (k - KIp)]; }
    out[e] = f2b(v);
}

// ---- x pre-transpose: x[B,F,T] -> xT[branch][samp][t][64] (f-padded to 64).
// LDS-tiled so both global read (1740 contiguous floats) and write (1920
// contiguous) are coalesced. Kills the stride-120B scattered x loads that were
// ~1 GB of HBM over-fetch inside the hot lstm loop.
__global__ __launch_bounds__(256) void prep_xt(const float* __restrict__ x1,
                                               const float* __restrict__ x2,
                                               float* __restrict__ xT)
{
    __shared__ float tile[1740];
    int blk = blockIdx.x;               // [0, 8192): br*4096 + s
    int br = blk >> 12;
    int s  = blk & 4095;
    const float* xp = (br ? x2 : x1) + (size_t)s * 1740;
    for (int i = threadIdx.x; i < 1740; i += 256) tile[i] = xp[i];
    __syncthreads();
    float* dst = xT + (size_t)blk * 1920;
    for (int i = threadIdx.x; i < 1920; i += 256) {
        int t = i >> 6, f = i & 63;
        dst[i] = (f < 58) ? tile[f * 30 + t] : 0.0f;
    }
}

// ---- Head weight transposes (o-fastest float4 blocks)
__global__ __launch_bounds__(256) void pack_wt1(const float* __restrict__ Wf1, float4* __restrict__ WT1)
{
    int e = blockIdx.x * 256 + threadIdx.x;
    if (e >= 480 * 1024) return;
    int kc = e >> 10, o = e & 1023;
    float4 v = {0.0f, 0.0f, 0.0f, 0.0f};
    if (o < 960) {
        const float* p = Wf1 + (size_t)o * 1920 + kc * 4;
        v.x = p[0]; v.y = p[1]; v.z = p[2]; v.w = p[3];
    }
    WT1[e] = v;
}
__global__ __launch_bounds__(256) void pack_wt2(const float* __restrict__ Wf2, float4* __restrict__ WT2)
{
    int e = blockIdx.x * 256 + threadIdx.x;
    if (e >= 256 * 512) return;
    int kc = e >> 9, o = e & 511;
    float4 v = {0.0f, 0.0f, 0.0f, 0.0f};
    if (o < 480) {
        int k = kc * 4;
        v.x = (k + 0 < 960) ? Wf2[(size_t)o * 960 + k + 0] : 0.0f;
        v.y = (k + 1 < 960) ? Wf2[(size_t)o * 960 + k + 1] : 0.0f;
        v.z = (k + 2 < 960) ? Wf2[(size_t)o * 960 + k + 2] : 0.0f;
        v.w = (k + 3 < 960) ? Wf2[(size_t)o * 960 + k + 3] : 0.0f;
    }
    WT2[e] = v;
}

#define MFMA32(A, X, B) A = __builtin_amdgcn_mfma_f32_32x32x16_bf16((X), (B), (A), 0, 0, 0)
#define MFMA16(A, X, B) A = __builtin_amdgcn_mfma_f32_16x16x32_bf16((X), (B), (A), 0, 0, 0)

// L1 A-fragment load (x for s<4, h1 otherwise); activations stay hi/lo.
#define L1_LOAD_A(SV) do { \
    if ((SV) < 4) { \
        const int _off = (SV) * 16 + kh * 8; \
        ahi = *(const short8*)(xh + n1 * 72 + _off); \
        alo = *(const short8*)(xl + n1 * 72 + _off); \
    } else { \
        const int _off = ((SV) - 4) * 16 + kh * 8; \
        ahi = *(const short8*)(h1hi + n1 * 520 + _off); \
        alo = *(const short8*)(h1lo + n1 * 520 + _off); \
    } } while (0)

// one L1 k-step of a 2-gate pass: 4 MFMAs (ahi,alo x gateA,gateB), then refill
// the just-freed weight set with the step 3 ahead (depth-3 rotation).
#define L1_SUB(WA, WB, IDX, GOFF) do { \
    const int _s = rev ? (35 - (ss + (IDX))) : (ss + (IDX)); \
    short8 ahi, alo; \
    L1_LOAD_A(_s); \
    MFMA32(P0, ahi, WA); \
    MFMA32(P1, ahi, WB); \
    MFMA32(P0, alo, WA); \
    MFMA32(P1, alo, WB); \
    if (ss + (IDX) + 3 < 36) { \
        const int _sn = rev ? (35 - (ss + (IDX) + 3)) : (ss + (IDX) + 3); \
        const unsigned short* _bb = B1p + _sn * 32768 + (GOFF); \
        WA = *(const short8*)(_bb); \
        WB = *(const short8*)(_bb + 512); \
    } } while (0)

#define L1_KLOOP(GOFF) \
    _Pragma("unroll 1") \
    for (int ss = 0; ss < 36; ss += 3) { \
        L1_SUB(w0a, w0b, 0, GOFF); \
        L1_SUB(w1a, w1b, 1, GOFF); \
        L1_SUB(w2a, w2b, 2, GOFF); \
    }

// entry prefetch of the first 3 k-steps of a pass. RV = direction of that pass.
#define L1_ENTRY(GOFF, RV) do { \
    const int _s0 = (RV) ? 35 : 0, _s1 = (RV) ? 34 : 1, _s2 = (RV) ? 33 : 2; \
    const unsigned short* _b0 = B1p + _s0 * 32768 + (GOFF); \
    const unsigned short* _b1 = B1p + _s1 * 32768 + (GOFF); \
    const unsigned short* _b2 = B1p + _s2 * 32768 + (GOFF); \
    w0a = *(const short8*)(_b0); w0b = *(const short8*)(_b0 + 512); \
    w1a = *(const short8*)(_b1); w1b = *(const short8*)(_b1 + 512); \
    w2a = *(const short8*)(_b2); w2b = *(const short8*)(_b2 + 512); \
} while (0)

#define L2_LOAD_A(SV) do { \
    if ((SV) < 16) { \
        const int _off = (SV) * 32 + quad * 8; \
        short8 _a  = *(const short8*)(h1hi + row2 * 520 + _off); \
        short8 _al = *(const short8*)(h1lo + row2 * 520 + _off); \
        short8 _msk = _a >> 15; \
        ahi = _a & ~_msk; alo = _al & ~_msk; \
    } else { \
        const int _off = ((SV) - 16) * 32 + quad * 8; \
        ahi = *(const short8*)(h2hi + cur * 4352 + row2 * 136 + _off); \
        alo = *(const short8*)(h2lo + cur * 4352 + row2 * 136 + _off); \
    } } while (0)

// one L2 k-step, all 4 gates single-plane: 8 MFMAs, depth-2 ping-pong refill.
#define L2_SUB(Q0, Q1, Q2, Q3, IDX) do { \
    const int _s = rev ? (19 - (ss + (IDX))) : (ss + (IDX)); \
    short8 ahi, alo; \
    L2_LOAD_A(_s); \
    MFMA16(A0, ahi, Q0); \
    MFMA16(A1, ahi, Q1); \
    MFMA16(A2, ahi, Q2); \
    MFMA16(A3, ahi, Q3); \
    MFMA16(A0, alo, Q0); \
    MFMA16(A1, alo, Q1); \
    MFMA16(A2, alo, Q2); \
    MFMA16(A3, alo, Q3); \
    if (ss + (IDX) + 2 < 20) { \
        const int _sn = rev ? (19 - (ss + (IDX) + 2)) : (ss + (IDX) + 2); \
        const unsigned short* _bb = B2p + _sn * 16384; \
        Q0 = *(const short8*)(_bb); \
        Q1 = *(const short8*)(_bb + 512); \
        Q2 = *(const short8*)(_bb + 1024); \
        Q3 = *(const short8*)(_bb + 1536); \
    } } while (0)

#define L2_ENTRY() do { \
    const int _s0 = rev ? 19 : 0, _s1 = rev ? 18 : 1; \
    const unsigned short* _b0 = B2p + _s0 * 16384; \
    const unsigned short* _b1 = B2p + _s1 * 16384; \
    qa0 = *(const short8*)(_b0);        qa1 = *(const short8*)(_b0 + 512); \
    qa2 = *(const short8*)(_b0 + 1024); qa3 = *(const short8*)(_b0 + 1536); \
    qb0 = *(const short8*)(_b1);        qb1 = *(const short8*)(_b1 + 512); \
    qb2 = *(const short8*)(_b1 + 1024); qb3 = *(const short8*)(_b1 + 1536); \
} while (0)

#define L3_LOAD_A(SV) do { \
    if ((SV) < 4) { \
        const int _off = (SV) * 32 + quad * 8; \
        short8 _a  = *(const short8*)(h2hi + nxt * 4352 + row3 * 136 + _off); \
        short8 _al = *(const short8*)(h2lo + nxt * 4352 + row3 * 136 + _off); \
        short8 _msk = _a >> 15; \
        ahi = _a & ~_msk; alo = _al & ~_msk; \
    } else { \
        const int _off = ((SV) - 4) * 32 + quad * 8; \
        ahi = *(const short8*)(h3hi + cur * 2304 + row3 * 72 + _off); \
        alo = *(const short8*)(h3lo + cur * 2304 + row3 * 72 + _off); \
    } } while (0)

#define L3_SUB(Q0, Q1, Q2, Q3, IDX) do { \
    const int _s = rev ? (5 - (ss + (IDX))) : (ss + (IDX)); \
    short8 ahi, alo; \
    L3_LOAD_A(_s); \
    MFMA16(A0, ahi, Q0); \
    MFMA16(A1, ahi, Q1); \
    MFMA16(A2, ahi, Q2); \
    MFMA16(A3, ahi, Q3); \
    MFMA16(A0, alo, Q0); \
    MFMA16(A1, alo, Q1); \
    MFMA16(A2, alo, Q2); \
    MFMA16(A3, alo, Q3); \
    if (ss + (IDX) + 2 < 6) { \
        const int _sn = rev ? (5 - (ss + (IDX) + 2)) : (ss + (IDX) + 2); \
        const unsigned short* _bb = B3p + _sn * 8192; \
        Q0 = *(const short8*)(_bb); \
        Q1 = *(const short8*)(_bb + 512); \
        Q2 = *(const short8*)(_bb + 1024); \
        Q3 = *(const short8*)(_bb + 1536); \
    } } while (0)

#define L3_ENTRY_A() do { \
    const int _s0 = rev ? 5 : 0; \
    const unsigned short* _b0 = B3p + _s0 * 8192; \
    ra0 = *(const short8*)(_b0);        ra1 = *(const short8*)(_b0 + 512); \
    ra2 = *(const short8*)(_b0 + 1024); ra3 = *(const short8*)(_b0 + 1536); \
} while (0)

#define L3_ENTRY_B() do { \
    const int _s1 = rev ? 4 : 1; \
    const unsigned short* _b1 = B3p + _s1 * 8192; \
    rb0 = *(const short8*)(_b1);        rb1 = *(const short8*)(_b1 + 512); \
    rb2 = *(const short8*)(_b1 + 1024); rb3 = *(const short8*)(_b1 + 1536); \
} while (0)

// ---- Fused Siamese 3-layer LSTM. 256 WGs x 1024 thr (16 waves, 4/SIMD), 135KB LDS.
// Round-13 (v6): v5 + two waste cuts (numerics identical to v5):
//  (a) x pre-transposed on device (xT[br][s][t][64]) -> staging loads are fully
//      coalesced (256B runs) instead of stride-120B scatter (~1 GB HBM over-fetch
//      + TA serialization inside the hot loop). Falls back to direct x reads if
//      the workspace can't hold xT.
//  (b) arch-VGPR pressure trim: only L3 set A (16 regs) is carried across
//      barrier D; set B is fetched after the barrier under the first L3_SUB's
//      MFMA cover. (VGPR_Count=64 arch + 64 AGPR: the arch half is the spill
//      driver -> WRITE_SIZE is the spill gauge.)
__global__ __launch_bounds__(1024, 4) void lstm3_v6(
    const float* __restrict__ x1, const float* __restrict__ x2,
    const float* __restrict__ xt, const int xtmode,
    const unsigned short* __restrict__ l1w, const unsigned short* __restrict__ l2w,
    const unsigned short* __restrict__ l3w,
    const float* __restrict__ b1, const float* __restrict__ b2, const float* __restrict__ b3,
    float* __restrict__ dbuf)
{
    extern __shared__ unsigned short sm[];
    unsigned short* h1hi = sm;                    // [32][520]
    unsigned short* h1lo = h1hi + 32 * 520;
    unsigned short* h2hi = h1lo + 32 * 520;       // [2][32][136]
    unsigned short* h2lo = h2hi + 2 * 32 * 136;
    unsigned short* h3hi = h2lo + 2 * 32 * 136;   // [2][32][72]
    unsigned short* h3lo = h3hi + 2 * 32 * 72;
    unsigned short* xhi  = h3lo + 2 * 32 * 72;    // [2][32][72] double-buffered
    unsigned short* xlo  = xhi  + 2 * 32 * 72;

    const int tid  = threadIdx.x;
    const int wv   = tid >> 6;
    const int lane = tid & 63;
    const int wg   = blockIdx.x;
    const int samp0 = wg * 16;

    {
        unsigned int* p = (unsigned int*)sm;
        for (int i = tid; i < 29952; i += 1024) p[i] = 0u;
    }

    // L1 lane mapping (32x32)
    const int n1 = lane & 31;
    const int kh = lane >> 5;
    const int u1 = wv * 32 + n1;
    // L2/L3 lane mapping (16x16)
    const int n2   = lane & 15;
    const int quad = lane >> 4;
    const int mt2  = wv >> 3, cg2 = wv & 7;
    const int u2   = cg2 * 16 + n2;
    const int row2 = mt2 * 16 + n2;
    const int mt3  = (wv >> 2) & 1, cg3 = wv & 3;
    const int u3   = cg3 * 16 + n2;
    const int row3 = mt3 * 16 + n2;

    float c1[16], c2[4], c3[4];
    #pragma unroll
    for (int r = 0; r < 16; ++r) c1[r] = 0.0f;
    #pragma unroll
    for (int r = 0; r < 4; ++r) { c2[r] = 0.0f; c3[r] = 0.0f; }

    const unsigned short* B1p = l1w + wv * 2048 + lane * 8;
    const unsigned short* B2p = l2w + cg2 * 2048 + lane * 8;
    const unsigned short* B3p = l3w + cg3 * 2048 + lane * 8;

    // register pools
    short8 w0a, w0b, w1a, w1b, w2a, w2b;             // L1 rotation (24 VGPR)
    short8 qa0, qa1, qa2, qa3, qb0, qb1, qb2, qb3;   // L2 ping-pong (32 VGPR)
    short8 ra0, ra1, ra2, ra3, rb0, rb1, rb2, rb3;   // L3 ping-pong (32 VGPR)

    // t=0 pass0 entry prefetch (fwd direction, gates i,f)
    L1_ENTRY(0, false);

    // stage x_0 into parity-0 buffer (prologue)
    for (int e = tid; e < 2048; e += 1024) {
        int b = e >> 6, f = e & 63;
        float v;
        if (xtmode) {
            int br = (b < 16) ? 0 : 1;
            v = xt[((size_t)(br * 4096 + samp0 + (b & 15)) * 30 + 0) * 64 + f];
        } else {
            const float* __restrict__ xp = (b < 16) ? x1 : x2;
            v = (f < 58) ? xp[(samp0 + (b & 15)) * 1740 + f * 30 + 0] : 0.0f;
        }
        unsigned short hi = f2b(v);
        xhi[b * 72 + f] = hi;
        xlo[b * 72 + f] = f2b(v - b2f(hi));
    }
    bar_lds();

    int cur = 0;
    #pragma unroll 1
    for (int t = 0; t < NTIME; ++t) {
        const bool rev = (t & 1);
        const int nxt = cur ^ 1;
        const unsigned short* xh = xhi + (t & 1) * 2304;
        const unsigned short* xl = xlo + (t & 1) * 2304;

        float i1[16];   // sigmoid(i-gate), carried pass0 -> pass1

        // ===== L1 pass 0: gates i,f =====
        {
            f32x16 P0, P1;
            #pragma unroll
            for (int r = 0; r < 16; ++r) { P0[r] = 0.0f; P1[r] = 0.0f; }
            float bg0 = b1[u1], bg1 = b1[512 + u1];
            L1_KLOOP(0);
            L1_ENTRY(1024, rev);      // pass1 entry (gates g,o), hides under epilogue
            #pragma unroll
            for (int r = 0; r < 16; ++r) {
                i1[r] = sigf(P0[r] + bg0);
                c1[r] *= sigf(P1[r] + bg1);
            }
        }
        // ===== L1 pass 1: gates g,o =====
        {
            f32x16 P0, P1;
            #pragma unroll
            for (int r = 0; r < 16; ++r) { P0[r] = 0.0f; P1[r] = 0.0f; }
            float bg0 = b1[1024 + u1], bg1 = b1[1536 + u1];
            L1_KLOOP(1024);
            bar_lds();   // B: all reads of h1(t-1)/x(t) done
            #pragma unroll
            for (int r = 0; r < 16; ++r) {
                float G = tanhfast(P0[r] + bg0);
                float O = sigf(P1[r] + bg1);
                float c = c1[r] + i1[r] * G;
                c1[r] = c;
                float h = O * tanhfast(c);
                int row = (r & 3) + 8 * (r >> 2) + 4 * kh;   // verified 32x32 C-map
                unsigned short hh = f2b(h);
                h1hi[row * 520 + u1] = hh;
                h1lo[row * 520 + u1] = f2b(h - b2f(hh));
            }
        }
        bar_lds();   // C: h1(t) visible

        // x(t+1): issue global loads first, then L2 weight entry, LDS writes last.
        float xv0, xv1;
        if (t + 1 < NTIME) {
            int b = tid >> 6, f = tid & 63;
            if (xtmode) {
                const float* p0 = xt + ((size_t)(samp0 + b) * 30 + (t + 1)) * 64 + f;
                xv0 = p0[0];
                xv1 = p0[(size_t)4096 * 1920];
            } else {
                int idx = (samp0 + b) * 1740 + f * 30 + (t + 1);
                xv0 = (f < 58) ? x1[idx] : 0.0f;
                xv1 = (f < 58) ? x2[idx] : 0.0f;
            }
        }

        L2_ENTRY();   // L2 entry frags (overlaps x conversion + write)

        if (t + 1 < NTIME) {
            unsigned short* xh2 = xhi + ((t + 1) & 1) * 2304;
            unsigned short* xl2 = xlo + ((t + 1) & 1) * 2304;
            int b = tid >> 6, f = tid & 63;
            unsigned short h0 = f2b(xv0);
            xh2[b * 72 + f] = h0;
            xl2[b * 72 + f] = f2b(xv0 - b2f(h0));
            unsigned short h1_ = f2b(xv1);
            xh2[(16 + b) * 72 + f] = h1_;
            xl2[(16 + b) * 72 + f] = f2b(xv1 - b2f(h1_));
        }

        // ===== L2: single 4-gate pass; k = [relu(h1) 512 | h2 128], 20 ksteps =====
        {
            f32x4 A0 = {0.0f, 0.0f, 0.0f, 0.0f};
            f32x4 A1 = {0.0f, 0.0f, 0.0f, 0.0f};
            f32x4 A2 = {0.0f, 0.0f, 0.0f, 0.0f};
            f32x4 A3 = {0.0f, 0.0f, 0.0f, 0.0f};
            float bg0 = b2[u2], bg1 = b2[128 + u2], bg2 = b2[256 + u2], bg3 = b2[384 + u2];
            #pragma unroll 1
            for (int ss = 0; ss < 20; ss += 2) {
                L2_SUB(qa0, qa1, qa2, qa3, 0);
                L2_SUB(qb0, qb1, qb2, qb3, 1);
            }
            if (wv < 8) { L3_ENTRY_A(); }   // only set A (16 regs) across bar D
            #pragma unroll
            for (int r = 0; r < 4; ++r) {
                float I = sigf(A0[r] + bg0);
                float F = sigf(A1[r] + bg1);
                float G = tanhfast(A2[r] + bg2);
                float O = sigf(A3[r] + bg3);
                float c = F * c2[r] + I * G;
                c2[r] = c;
                float h = O * tanhfast(c);
                int row = mt2 * 16 + quad * 4 + r;
                unsigned short hh = f2b(h);
                h2hi[nxt * 4352 + row * 136 + u2] = hh;
                h2lo[nxt * 4352 + row * 136 + u2] = f2b(h - b2f(hh));
            }
        }
        bar_lds();   // D: h2(t) + x(t+1) visible

        // ===== L3: single 4-gate pass; k = [relu(h2) 128 | h3 64], 6 ksteps, waves 0-7 =====
        if (wv < 8) {
            f32x4 A0 = {0.0f, 0.0f, 0.0f, 0.0f};
            f32x4 A1 = {0.0f, 0.0f, 0.0f, 0.0f};
            f32x4 A2 = {0.0f, 0.0f, 0.0f, 0.0f};
            f32x4 A3 = {0.0f, 0.0f, 0.0f, 0.0f};
            float bg0 = b3[u3], bg1 = b3[64 + u3], bg2 = b3[128 + u3], bg3 = b3[192 + u3];
            L3_ENTRY_B();   // set B fetched post-barrier, covered by first L3_SUB
            #pragma unroll 1
            for (int ss = 0; ss < 6; ss += 2) {
                L3_SUB(ra0, ra1, ra2, ra3, 0);
                L3_SUB(rb0, rb1, rb2, rb3, 1);
            }
            #pragma unroll
            for (int r = 0; r < 4; ++r) {
                float I = sigf(A0[r] + bg0);
                float F = sigf(A1[r] + bg1);
                float G = tanhfast(A2[r] + bg2);
                float O = sigf(A3[r] + bg3);
                float c = F * c3[r] + I * G;
                c3[r] = c;
                float h = O * tanhfast(c);
                int row = mt3 * 16 + quad * 4 + r;
                unsigned short hh = f2b(h);
                h3hi[nxt * 2304 + row * 72 + u3] = hh;
                h3lo[nxt * 2304 + row * 72 + u3] = f2b(h - b2f(hh));
            }
        }

        // next-t pass0 entry prefetch: issued before bar E + d-write, survives the
        // backedge (LDS-only barriers keep vmcnt).
        if (t + 1 < NTIME) {
            L1_ENTRY(0, !rev);
        }
        bar_lds();   // E: h3(t) visible

        // d = |relu(h3_x1) - relu(h3_x2)| -> global
        {
            int b = tid >> 6, u = tid & 63;
            float ha = b2f(h3hi[nxt * 2304 + b * 72 + u]) + b2f(h3lo[nxt * 2304 + b * 72 + u]);
            float hb = b2f(h3hi[nxt * 2304 + (16 + b) * 72 + u]) + b2f(h3lo[nxt * 2304 + (16 + b) * 72 + u]);
            dbuf[(size_t)(samp0 + b) * 1920 + t * 64 + u] = fabsf(fmaxf(ha, 0.0f) - fmaxf(hb, 0.0f));
        }
        cur = nxt;
    }
}

// ---- FC head v2
__global__ __launch_bounds__(512) void head_v2(
    const float* __restrict__ dg,
    const float4* __restrict__ WT1, const float* __restrict__ bf1,
    const float4* __restrict__ WT2, const float* __restrict__ bf2,
    const float* __restrict__ Wf3, const float* __restrict__ bf3,
    const float* __restrict__ Wf4, const float* __restrict__ bf4,
    float* __restrict__ out)
{
    extern __shared__ float hds[];
    float* ds = hds;                  // [16][1928] during fc1
    float* a1 = hds;                  // [16][1032] overlay after fc1
    float* a2 = a1 + 16 * 1032;       // [16][520]
    float* a3 = a2 + 16 * 520;        // [16][16]

    const int tid = threadIdx.x;
    const int samp0 = blockIdx.x * 16;

    for (int e = tid; e < 16 * 480; e += 512) {
        int b = e / 480, jc = e - b * 480;
        const float* src = dg + (size_t)(samp0 + b) * 1920 + jc * 4;
        float* dst = ds + b * 1928 + jc * 4;
        dst[0] = src[0]; dst[1] = src[1]; dst[2] = src[2]; dst[3] = src[3];
    }
    __syncthreads();

    const int w = tid >> 6, lane = tid & 63;
    const int oA = w * 128 + lane, oB = oA + 64;
    float accA[16], accB[16];
    {
        float bA = (oA < 960) ? bf1[oA] : 0.0f;
        float bB = (oB < 960) ? bf1[oB] : 0.0f;
        #pragma unroll
        for (int r = 0; r < 16; ++r) { accA[r] = bA; accB[r] = bB; }
    }
    #pragma unroll 2
    for (int kc = 0; kc < 480; ++kc) {
        float4 wA = WT1[kc * 1024 + oA];
        float4 wB = WT1[kc * 1024 + oB];
        #pragma unroll
        for (int r = 0; r < 16; ++r) {
            float4 d4 = ((const float4*)(ds + r * 1928))[kc];
            accA[r] += d4.x * wA.x + d4.y * wA.y + d4.z * wA.z + d4.w * wA.w;
            accB[r] += d4.x * wB.x + d4.y * wB.y + d4.z * wB.z + d4.w * wB.w;
        }
    }
    __syncthreads();
    #pragma unroll
    for (int r = 0; r < 16; ++r) {
        a1[r * 1032 + oA] = fmaxf(accA[r], 0.0f);
        a1[r * 1032 + oB] = fmaxf(accB[r], 0.0f);
    }
    __syncthreads();

    const int o2 = tid;
    float acc2[16];
    {
        float b = (o2 < 480) ? bf2[o2] : 0.0f;
        #pragma unroll
        for (int r = 0; r < 16; ++r) acc2[r] = b;
    }
    #pragma unroll 2
    for (int kc = 0; kc < 256; ++kc) {
        float4 w4 = WT2[kc * 512 + o2];
        #pragma unroll
        for (int r = 0; r < 16; ++r) {
            float4 a4 = ((const float4*)(a1 + r * 1032))[kc];
            acc2[r] += a4.x * w4.x + a4.y * w4.y + a4.z * w4.z + a4.w * w4.w;
        }
    }
    #pragma unroll
    for (int r = 0; r < 16; ++r) a2[r * 520 + o2] = fmaxf(acc2[r], 0.0f);
    __syncthreads();

    if (tid < 256) {
        int o = tid & 15, r = tid >> 4;
        float acc = bf3[o];
        const float4* wr = (const float4*)(Wf3 + (size_t)o * 480);
        const float4* av = (const float4*)(a2 + r * 520);
        #pragma unroll 4
        for (int kc = 0; kc < 120; ++kc) {
            float4 a4 = av[kc];
            float4 w4 = wr[kc];
            acc += a4.x * w4.x + a4.y * w4.y + a4.z * w4.z + a4.w * w4.w;
        }
        a3[r * 16 + o] = fmaxf(acc, 0.0f);
    }
    __syncthreads();

    if (tid < 16) {
        float acc = bf4[0];
        #pragma unroll
        for (int k = 0; k < 16; ++k) acc += a3[tid * 16 + k] * Wf4[k];
        out[samp0 + tid] = acc;
    }
}

extern "C" void kernel_launch(void* const* d_in, const int* in_sizes, int n_in,
                              void* d_out, int out_size, void* d_ws, size_t ws_size,
                              hipStream_t stream) {
    const float* x1   = (const float*)d_in[0];
    const float* x2   = (const float*)d_in[1];
    const float* Wih1 = (const float*)d_in[2];
    const float* Whh1 = (const float*)d_in[3];
    const float* b1   = (const float*)d_in[4];
    const float* Wih2 = (const float*)d_in[5];
    const float* Whh2 = (const float*)d_in[6];
    const float* b2   = (const float*)d_in[7];
    const float* Wih3 = (const float*)d_in[8];
    const float* Whh3 = (const float*)d_in[9];
    const float* b3   = (const float*)d_in[10];
    const float* Wf1  = (const float*)d_in[11];
    const float* bf1  = (const float*)d_in[12];
    const float* Wf2  = (const float*)d_in[13];
    const float* bf2  = (const float*)d_in[14];
    const float* Wf3  = (const float*)d_in[15];
    const float* bf3  = (const float*)d_in[16];
    const float* Wf4  = (const float*)d_in[17];
    const float* bf4  = (const float*)d_in[18];

    float* wsf = (float*)d_ws;
    float* dbuf = wsf;                                         // 4096*1920 = 7,864,320 f32
    unsigned short* l1w = (unsigned short*)(wsf + 7864320);    // 36*32768 = 1,179,648 us
    unsigned short* l2w = l1w + 1179648;                       // 20*8*2048 =  327,680 us
    unsigned short* l3w = l2w + 327680;                        //  6*4*2048 =   49,152 us
    float4* WT1 = (float4*)(wsf + 8642560);                    // 480*1024 float4
    float4* WT2 = WT1 + 480 * 1024;                            // 256*512  float4
    float* xT   = wsf + 11132928;                              // 2*4096*30*64 = 15,728,640 f32
    float* out = (float*)d_out;

    const size_t need_bytes = (size_t)(11132928 + 15728640) * 4u;
    const int xtmode = (ws_size >= need_bytes) ? 1 : 0;

    prep_w32s<<<(36 * 32768) / 256, 256, 0, stream>>>(Wih1, Whh1, l1w);
    prep_w16s<<<(20 * 8 * 2048) / 256, 256, 0, stream>>>(Wih2, Whh2, l2w, 128, 512, 512, 128, 8, 20);
    prep_w16s<<<(6 * 4 * 2048) / 256, 256, 0, stream>>>(Wih3, Whh3, l3w, 64, 128, 128, 64, 4, 6);
    pack_wt1<<<(480 * 1024) / 256, 256, 0, stream>>>(Wf1, WT1);
    pack_wt2<<<(256 * 512) / 256, 256, 0, stream>>>(Wf2, WT2);
    if (xtmode) {
        prep_xt<<<8192, 256, 0, stream>>>(x1, x2, xT);
    }

    (void)hipFuncSetAttribute((const void*)lstm3_v6,
                              hipFuncAttributeMaxDynamicSharedMemorySize, 138240);
    lstm3_v6<<<256, 1024, 138240, stream>>>(x1, x2, xT, xtmode,
                                            l1w, l2w, l3w, b1, b2, b3, dbuf);

    (void)hipFuncSetAttribute((const void*)head_v2,
                              hipFuncAttributeMaxDynamicSharedMemorySize, 16 * 1928 * 4);
    head_v2<<<256, 512, 16 * 1928 * 4, stream>>>(dbuf, WT1, bf1, WT2, bf2,
                                                 Wf3, bf3, Wf4, bf4, out);
}

// Round 6
// 2408.362 us; speedup vs baseline: 1.8045x; 1.1758x over previous
//
#include <hip/hip_runtime.h>

#define NTIME 30
#define NB 4096

typedef __attribute__((ext_vector_type(8))) short short8;
typedef __attribute__((ext_vector_type(8))) _Float16 half8;
typedef __attribute__((ext_vector_type(4))) float f32x4;
typedef __attribute__((ext_vector_type(16))) float f32x16;

__device__ __forceinline__ unsigned short f2h(float f) {
    _Float16 h = (_Float16)f;                  // RNE
    unsigned short u; __builtin_memcpy(&u, &h, 2); return u;
}
__device__ __forceinline__ float h2f(unsigned short u) {
    _Float16 h; __builtin_memcpy(&h, &u, 2); return (float)h;
}
__device__ __forceinline__ half8 s2h8(short8 s) {
    union { short8 s; half8 h; } u; u.s = s; return u.h;
}
__device__ __forceinline__ float sigf(float x)     { return 1.0f / (1.0f + __expf(-x)); }
__device__ __forceinline__ float tanhfast(float x) { return 1.0f - 2.0f / (__expf(2.0f * x) + 1.0f); }

// LDS-only barrier: all cross-wave communication inside lstm3 is via LDS, so we
// only need lgkmcnt(0)+s_barrier. Does NOT drain vmcnt -> global weight
// prefetches stay in flight across phase boundaries.
__device__ __forceinline__ void bar_lds() {
    asm volatile("s_waitcnt lgkmcnt(0)" ::: "memory");
    __builtin_amdgcn_s_barrier();
    asm volatile("" ::: "memory");
}

// ---- L1 weight pack: 32x32x16 B-frags, SINGLE fp16 plane (round-15).
__global__ __launch_bounds__(256) void prep_w32s(const float* __restrict__ Wih,
                                                 const float* __restrict__ Whh,
                                                 unsigned short* __restrict__ out)
{
    int e = blockIdx.x * 256 + threadIdx.x;
    if (e >= 36 * 32768) return;
    int j    = e & 7;
    int lane = (e >> 3) & 63;
    int g    = (e >> 9) & 3;
    int w    = (e >> 11) & 15;
    int s    = e >> 15;
    int n = lane & 31, kh = lane >> 5;
    int unit = w * 32 + n;
    int k = s * 16 + kh * 8 + j;
    int row = g * 512 + unit;
    float v = 0.0f;
    if (k < 64) { if (k < 58) v = Wih[row * 58 + k]; }
    else        { v = Whh[row * 512 + (k - 64)]; }
    out[e] = f2h(v);
}

// ---- L2/L3 weight pack: 16x16x32 B-frags, single fp16 plane.
__global__ __launch_bounds__(256) void prep_w16s(const float* __restrict__ Wih,
                                                 const float* __restrict__ Whh,
                                                 unsigned short* __restrict__ out,
                                                 int H, int KI, int KIp, int KH, int CG, int KS)
{
    int e = blockIdx.x * 256 + threadIdx.x;
    if (e >= KS * CG * 2048) return;
    int j    = e & 7;
    int lane = (e >> 3) & 63;
    int g    = (e >> 9) & 3;
    int rest = e >> 11;
    int cg = rest % CG;
    int s  = rest / CG;
    int n = lane & 15, q = lane >> 4;
    int unit = cg * 16 + n;
    int k = s * 32 + q * 8 + j;
    int row = g * H + unit;
    float v = 0.0f;
    if (k < KIp) { if (k < KI) v = Wih[row * KI + k]; }
    else         { v = Whh[row * KH + (k - KIp)]; }
    out[e] = f2h(v);
}

// ---- x pre-transpose: x[B,F,T] -> xT[branch][samp][t][64] (f-padded to 64).
__global__ __launch_bounds__(256) void prep_xt(const float* __restrict__ x1,
                                               const float* __restrict__ x2,
                                               float* __restrict__ xT)
{
    __shared__ float tile[1740];
    int blk = blockIdx.x;               // [0, 8192): br*4096 + s
    int br = blk >> 12;
    int s  = blk & 4095;
    const float* xp = (br ? x2 : x1) + (size_t)s * 1740;
    for (int i = threadIdx.x; i < 1740; i += 256) tile[i] = xp[i];
    __syncthreads();
    float* dst = xT + (size_t)blk * 1920;
    for (int i = threadIdx.x; i < 1920; i += 256) {
        int t = i >> 6, f = i & 63;
        dst[i] = (f < 58) ? tile[f * 30 + t] : 0.0f;
    }
}

// ---- Head weight transposes (o-fastest float4 blocks)
__global__ __launch_bounds__(256) void pack_wt1(const float* __restrict__ Wf1, float4* __restrict__ WT1)
{
    int e = blockIdx.x * 256 + threadIdx.x;
    if (e >= 480 * 1024) return;
    int kc = e >> 10, o = e & 1023;
    float4 v = {0.0f, 0.0f, 0.0f, 0.0f};
    if (o < 960) {
        const float* p = Wf1 + (size_t)o * 1920 + kc * 4;
        v.x = p[0]; v.y = p[1]; v.z = p[2]; v.w = p[3];
    }
    WT1[e] = v;
}
__global__ __launch_bounds__(256) void pack_wt2(const float* __restrict__ Wf2, float4* __restrict__ WT2)
{
    int e = blockIdx.x * 256 + threadIdx.x;
    if (e >= 256 * 512) return;
    int kc = e >> 9, o = e & 511;
    float4 v = {0.0f, 0.0f, 0.0f, 0.0f};
    if (o < 480) {
        int k = kc * 4;
        v.x = (k + 0 < 960) ? Wf2[(size_t)o * 960 + k + 0] : 0.0f;
        v.y = (k + 1 < 960) ? Wf2[(size_t)o * 960 + k + 1] : 0.0f;
        v.z = (k + 2 < 960) ? Wf2[(size_t)o * 960 + k + 2] : 0.0f;
        v.w = (k + 3 < 960) ? Wf2[(size_t)o * 960 + k + 3] : 0.0f;
    }
    WT2[e] = v;
}

#define MFMA32(A, X, B) A = __builtin_amdgcn_mfma_f32_32x32x16_f16((X), (B), (A), 0, 0, 0)
#define MFMA16(A, X, B) A = __builtin_amdgcn_mfma_f32_16x16x32_f16((X), (B), (A), 0, 0, 0)

// L1 A-fragment load (x for s<4, h1 otherwise); single-plane fp16 activations.
#define L1_LOAD_A(SV) do { \
    if ((SV) < 4) { \
        a = *(const half8*)(xh + n1 * 72 + (SV) * 16 + kh * 8); \
    } else { \
        a = *(const half8*)(h1b + n1 * 520 + ((SV) - 4) * 16 + kh * 8); \
    } } while (0)

// one L1 k-step of a 2-gate pass: 2 MFMAs, depth-3 rotating refill.
#define L1_SUB(WA, WB, IDX, GOFF) do { \
    const int _s = rev ? (35 - (ss + (IDX))) : (ss + (IDX)); \
    half8 a; \
    L1_LOAD_A(_s); \
    MFMA32(P0, a, WA); \
    MFMA32(P1, a, WB); \
    if (ss + (IDX) + 3 < 36) { \
        const int _sn = rev ? (35 - (ss + (IDX) + 3)) : (ss + (IDX) + 3); \
        const unsigned short* _bb = B1p + _sn * 32768 + (GOFF); \
        WA = *(const half8*)(_bb); \
        WB = *(const half8*)(_bb + 512); \
    } } while (0)

#define L1_KLOOP(GOFF) \
    _Pragma("unroll 1") \
    for (int ss = 0; ss < 36; ss += 3) { \
        L1_SUB(w0a, w0b, 0, GOFF); \
        L1_SUB(w1a, w1b, 1, GOFF); \
        L1_SUB(w2a, w2b, 2, GOFF); \
    }

// entry prefetch of the first 3 k-steps of a pass. RV = direction of that pass.
#define L1_ENTRY(GOFF, RV) do { \
    const int _s0 = (RV) ? 35 : 0, _s1 = (RV) ? 34 : 1, _s2 = (RV) ? 33 : 2; \
    const unsigned short* _b0 = B1p + _s0 * 32768 + (GOFF); \
    const unsigned short* _b1 = B1p + _s1 * 32768 + (GOFF); \
    const unsigned short* _b2 = B1p + _s2 * 32768 + (GOFF); \
    w0a = *(const half8*)(_b0); w0b = *(const half8*)(_b0 + 512); \
    w1a = *(const half8*)(_b1); w1b = *(const half8*)(_b1 + 512); \
    w2a = *(const half8*)(_b2); w2b = *(const half8*)(_b2 + 512); \
} while (0)

#define L2_LOAD_A(SV) do { \
    if ((SV) < 16) { \
        short8 _a = *(const short8*)(h1b + row2 * 520 + (SV) * 32 + quad * 8); \
        short8 _msk = _a >> 15; \
        a = s2h8(_a & ~_msk); \
    } else { \
        a = *(const half8*)(h2b + cur * 4352 + row2 * 136 + ((SV) - 16) * 32 + quad * 8); \
    } } while (0)

// one L2 k-step, all 4 gates: 4 MFMAs, depth-2 ping-pong refill.
#define L2_SUB(Q0, Q1, Q2, Q3, IDX) do { \
    const int _s = rev ? (19 - (ss + (IDX))) : (ss + (IDX)); \
    half8 a; \
    L2_LOAD_A(_s); \
    MFMA16(A0, a, Q0); \
    MFMA16(A1, a, Q1); \
    MFMA16(A2, a, Q2); \
    MFMA16(A3, a, Q3); \
    if (ss + (IDX) + 2 < 20) { \
        const int _sn = rev ? (19 - (ss + (IDX) + 2)) : (ss + (IDX) + 2); \
        const unsigned short* _bb = B2p + _sn * 16384; \
        Q0 = *(const half8*)(_bb); \
        Q1 = *(const half8*)(_bb + 512); \
        Q2 = *(const half8*)(_bb + 1024); \
        Q3 = *(const half8*)(_bb + 1536); \
    } } while (0)

#define L2_ENTRY() do { \
    const int _s0 = rev ? 19 : 0, _s1 = rev ? 18 : 1; \
    const unsigned short* _b0 = B2p + _s0 * 16384; \
    const unsigned short* _b1 = B2p + _s1 * 16384; \
    qa0 = *(const half8*)(_b0);        qa1 = *(const half8*)(_b0 + 512); \
    qa2 = *(const half8*)(_b0 + 1024); qa3 = *(const half8*)(_b0 + 1536); \
    qb0 = *(const half8*)(_b1);        qb1 = *(const half8*)(_b1 + 512); \
    qb2 = *(const half8*)(_b1 + 1024); qb3 = *(const half8*)(_b1 + 1536); \
} while (0)

#define L3_LOAD_A(SV) do { \
    if ((SV) < 4) { \
        short8 _a = *(const short8*)(h2b + nxt * 4352 + row3 * 136 + (SV) * 32 + quad * 8); \
        short8 _msk = _a >> 15; \
        a = s2h8(_a & ~_msk); \
    } else { \
        a = *(const half8*)(h3b + cur * 2304 + row3 * 72 + ((SV) - 4) * 32 + quad * 8); \
    } } while (0)

#define L3_SUB(Q0, Q1, Q2, Q3, IDX) do { \
    const int _s = rev ? (5 - (ss + (IDX))) : (ss + (IDX)); \
    half8 a; \
    L3_LOAD_A(_s); \
    MFMA16(A0, a, Q0); \
    MFMA16(A1, a, Q1); \
    MFMA16(A2, a, Q2); \
    MFMA16(A3, a, Q3); \
    if (ss + (IDX) + 2 < 6) { \
        const int _sn = rev ? (5 - (ss + (IDX) + 2)) : (ss + (IDX) + 2); \
        const unsigned short* _bb = B3p + _sn * 8192; \
        Q0 = *(const half8*)(_bb); \
        Q1 = *(const half8*)(_bb + 512); \
        Q2 = *(const half8*)(_bb + 1024); \
        Q3 = *(const half8*)(_bb + 1536); \
    } } while (0)

#define L3_ENTRY_A() do { \
    const int _s0 = rev ? 5 : 0; \
    const unsigned short* _b0 = B3p + _s0 * 8192; \
    ra0 = *(const half8*)(_b0);        ra1 = *(const half8*)(_b0 + 512); \
    ra2 = *(const half8*)(_b0 + 1024); ra3 = *(const half8*)(_b0 + 1536); \
} while (0)

#define L3_ENTRY_B() do { \
    const int _s1 = rev ? 4 : 1; \
    const unsigned short* _b1 = B3p + _s1 * 8192; \
    rb0 = *(const half8*)(_b1);        rb1 = *(const half8*)(_b1 + 512); \
    rb2 = *(const half8*)(_b1 + 1024); rb3 = *(const half8*)(_b1 + 1536); \
} while (0)

// ---- Fused Siamese 3-layer LSTM. 256 WGs x 1024 thr (16 waves, 4/SIMD), 69KB LDS.
// Round-15 (v8): v7's halved-cost structure with FP16 storage instead of bf16.
// v7 failed accuracy at 2.29e-4 (threshold 1.758e-4); error decomposition shows
// the bf16 activation-storage term (~1.7e-4, 2^-9 relative) dominates. All values
// are range-tiny (|W|<=0.13, |h|<1, |x|<~5) -> fp16's 3 extra mantissa bits cut
// storage error 8x (2^-12). gfx950 f16 MFMAs run at the bf16 rate with identical
// fragment geometry, so the cost structure is unchanged: MFMA count halved vs v6,
// LDS traffic halved, staging VALU halved. Expect absmax ~5-8e-5.
__global__ __launch_bounds__(1024, 4) void lstm3_v8(
    const float* __restrict__ x1, const float* __restrict__ x2,
    const float* __restrict__ xt, const int xtmode,
    const unsigned short* __restrict__ l1w, const unsigned short* __restrict__ l2w,
    const unsigned short* __restrict__ l3w,
    const float* __restrict__ b1, const float* __restrict__ b2, const float* __restrict__ b3,
    float* __restrict__ dbuf)
{
    extern __shared__ unsigned short sm[];
    unsigned short* h1b = sm;                    // [32][520]
    unsigned short* h2b = h1b + 32 * 520;        // [2][32][136]
    unsigned short* h3b = h2b + 2 * 32 * 136;    // [2][32][72]
    unsigned short* xb  = h3b + 2 * 32 * 72;     // [2][32][72] double-buffered
    // total 34560 shorts = 69120 B

    const int tid  = threadIdx.x;
    const int wv   = tid >> 6;
    const int lane = tid & 63;
    const int wg   = blockIdx.x;
    const int samp0 = wg * 16;

    {
        unsigned int* p = (unsigned int*)sm;
        for (int i = tid; i < 17280; i += 1024) p[i] = 0u;
    }

    // L1 lane mapping (32x32)
    const int n1 = lane & 31;
    const int kh = lane >> 5;
    const int u1 = wv * 32 + n1;
    // L2/L3 lane mapping (16x16)
    const int n2   = lane & 15;
    const int quad = lane >> 4;
    const int mt2  = wv >> 3, cg2 = wv & 7;
    const int u2   = cg2 * 16 + n2;
    const int row2 = mt2 * 16 + n2;
    const int mt3  = (wv >> 2) & 1, cg3 = wv & 3;
    const int u3   = cg3 * 16 + n2;
    const int row3 = mt3 * 16 + n2;

    float c1[16], c2[4], c3[4];
    #pragma unroll
    for (int r = 0; r < 16; ++r) c1[r] = 0.0f;
    #pragma unroll
    for (int r = 0; r < 4; ++r) { c2[r] = 0.0f; c3[r] = 0.0f; }

    const unsigned short* B1p = l1w + wv * 2048 + lane * 8;
    const unsigned short* B2p = l2w + cg2 * 2048 + lane * 8;
    const unsigned short* B3p = l3w + cg3 * 2048 + lane * 8;

    // register pools
    half8 w0a, w0b, w1a, w1b, w2a, w2b;             // L1 rotation (24 VGPR)
    half8 qa0, qa1, qa2, qa3, qb0, qb1, qb2, qb3;   // L2 ping-pong (32 VGPR)
    half8 ra0, ra1, ra2, ra3, rb0, rb1, rb2, rb3;   // L3 ping-pong (32 VGPR)

    // t=0 pass0 entry prefetch (fwd direction, gates i,f)
    L1_ENTRY(0, false);

    // stage x_0 into parity-0 buffer (prologue)
    for (int e = tid; e < 2048; e += 1024) {
        int b = e >> 6, f = e & 63;
        float v;
        if (xtmode) {
            int br = (b < 16) ? 0 : 1;
            v = xt[((size_t)(br * 4096 + samp0 + (b & 15)) * 30 + 0) * 64 + f];
        } else {
            const float* __restrict__ xp = (b < 16) ? x1 : x2;
            v = (f < 58) ? xp[(samp0 + (b & 15)) * 1740 + f * 30 + 0] : 0.0f;
        }
        xb[b * 72 + f] = f2h(v);
    }
    bar_lds();

    int cur = 0;
    #pragma unroll 1
    for (int t = 0; t < NTIME; ++t) {
        const bool rev = (t & 1);
        const int nxt = cur ^ 1;
        const unsigned short* xh = xb + (t & 1) * 2304;

        float i1[16];   // sigmoid(i-gate), carried pass0 -> pass1

        // ===== L1 pass 0: gates i,f =====
        {
            f32x16 P0, P1;
            #pragma unroll
            for (int r = 0; r < 16; ++r) { P0[r] = 0.0f; P1[r] = 0.0f; }
            float bg0 = b1[u1], bg1 = b1[512 + u1];
            L1_KLOOP(0);
            L1_ENTRY(1024, rev);      // pass1 entry (gates g,o), hides under epilogue
            #pragma unroll
            for (int r = 0; r < 16; ++r) {
                i1[r] = sigf(P0[r] + bg0);
                c1[r] *= sigf(P1[r] + bg1);
            }
        }
        // ===== L1 pass 1: gates g,o =====
        {
            f32x16 P0, P1;
            #pragma unroll
            for (int r = 0; r < 16; ++r) { P0[r] = 0.0f; P1[r] = 0.0f; }
            float bg0 = b1[1024 + u1], bg1 = b1[1536 + u1];
            L1_KLOOP(1024);
            bar_lds();   // B: all reads of h1(t-1)/x(t) done
            #pragma unroll
            for (int r = 0; r < 16; ++r) {
                float G = tanhfast(P0[r] + bg0);
                float O = sigf(P1[r] + bg1);
                float c = c1[r] + i1[r] * G;
                c1[r] = c;
                float h = O * tanhfast(c);
                int row = (r & 3) + 8 * (r >> 2) + 4 * kh;   // verified 32x32 C-map
                h1b[row * 520 + u1] = f2h(h);
            }
        }
        bar_lds();   // C: h1(t) visible

        // x(t+1): issue global loads first, then L2 weight entry, LDS writes last.
        float xv0, xv1;
        if (t + 1 < NTIME) {
            int b = tid >> 6, f = tid & 63;
            if (xtmode) {
                const float* p0 = xt + ((size_t)(samp0 + b) * 30 + (t + 1)) * 64 + f;
                xv0 = p0[0];
                xv1 = p0[(size_t)4096 * 1920];
            } else {
                int idx = (samp0 + b) * 1740 + f * 30 + (t + 1);
                xv0 = (f < 58) ? x1[idx] : 0.0f;
                xv1 = (f < 58) ? x2[idx] : 0.0f;
            }
        }

        L2_ENTRY();   // L2 entry frags (overlaps x conversion + write)

        if (t + 1 < NTIME) {
            unsigned short* xb2 = xb + ((t + 1) & 1) * 2304;
            int b = tid >> 6, f = tid & 63;
            xb2[b * 72 + f] = f2h(xv0);
            xb2[(16 + b) * 72 + f] = f2h(xv1);
        }

        // ===== L2: single 4-gate pass; k = [relu(h1) 512 | h2 128], 20 ksteps =====
        {
            f32x4 A0 = {0.0f, 0.0f, 0.0f, 0.0f};
            f32x4 A1 = {0.0f, 0.0f, 0.0f, 0.0f};
            f32x4 A2 = {0.0f, 0.0f, 0.0f, 0.0f};
            f32x4 A3 = {0.0f, 0.0f, 0.0f, 0.0f};
            float bg0 = b2[u2], bg1 = b2[128 + u2], bg2 = b2[256 + u2], bg3 = b2[384 + u2];
            #pragma unroll 1
            for (int ss = 0; ss < 20; ss += 2) {
                L2_SUB(qa0, qa1, qa2, qa3, 0);
                L2_SUB(qb0, qb1, qb2, qb3, 1);
            }
            if (wv < 8) { L3_ENTRY_A(); }   // only set A (16 regs) across bar D
            #pragma unroll
            for (int r = 0; r < 4; ++r) {
                float I = sigf(A0[r] + bg0);
                float F = sigf(A1[r] + bg1);
                float G = tanhfast(A2[r] + bg2);
                float O = sigf(A3[r] + bg3);
                float c = F * c2[r] + I * G;
                c2[r] = c;
                float h = O * tanhfast(c);
                int row = mt2 * 16 + quad * 4 + r;
                h2b[nxt * 4352 + row * 136 + u2] = f2h(h);
            }
        }
        bar_lds();   // D: h2(t) + x(t+1) visible

        // ===== L3: single 4-gate pass; k = [relu(h2) 128 | h3 64], 6 ksteps, waves 0-7 =====
        if (wv < 8) {
            f32x4 A0 = {0.0f, 0.0f, 0.0f, 0.0f};
            f32x4 A1 = {0.0f, 0.0f, 0.0f, 0.0f};
            f32x4 A2 = {0.0f, 0.0f, 0.0f, 0.0f};
            f32x4 A3 = {0.0f, 0.0f, 0.0f, 0.0f};
            float bg0 = b3[u3], bg1 = b3[64 + u3], bg2 = b3[128 + u3], bg3 = b3[192 + u3];
            L3_ENTRY_B();   // set B fetched post-barrier, covered by first L3_SUB
            #pragma unroll 1
            for (int ss = 0; ss < 6; ss += 2) {
                L3_SUB(ra0, ra1, ra2, ra3, 0);
                L3_SUB(rb0, rb1, rb2, rb3, 1);
            }
            #pragma unroll
            for (int r = 0; r < 4; ++r) {
                float I = sigf(A0[r] + bg0);
                float F = sigf(A1[r] + bg1);
                float G = tanhfast(A2[r] + bg2);
                float O = sigf(A3[r] + bg3);
                float c = F * c3[r] + I * G;
                c3[r] = c;
                float h = O * tanhfast(c);
                int row = mt3 * 16 + quad * 4 + r;
                h3b[nxt * 2304 + row * 72 + u3] = f2h(h);
            }
        }

        // next-t pass0 entry prefetch: issued before bar E + d-write, survives the
        // backedge (LDS-only barriers keep vmcnt).
        if (t + 1 < NTIME) {
            L1_ENTRY(0, !rev);
        }
        bar_lds();   // E: h3(t) visible

        // d = |relu(h3_x1) - relu(h3_x2)| -> global
        {
            int b = tid >> 6, u = tid & 63;
            float ha = h2f(h3b[nxt * 2304 + b * 72 + u]);
            float hb = h2f(h3b[nxt * 2304 + (16 + b) * 72 + u]);
            dbuf[(size_t)(samp0 + b) * 1920 + t * 64 + u] = fabsf(fmaxf(ha, 0.0f) - fmaxf(hb, 0.0f));
        }
        cur = nxt;
    }
}

// ---- FC head v2
__global__ __launch_bounds__(512) void head_v2(
    const float* __restrict__ dg,
    const float4* __restrict__ WT1, const float* __restrict__ bf1,
    const float4* __restrict__ WT2, const float* __restrict__ bf2,
    const float* __restrict__ Wf3, const float* __restrict__ bf3,
    const float* __restrict__ Wf4, const float* __restrict__ bf4,
    float* __restrict__ out)
{
    extern __shared__ float hds[];
    float* ds = hds;                  // [16][1928] during fc1
    float* a1 = hds;                  // [16][1032] overlay after fc1
    float* a2 = a1 + 16 * 1032;       // [16][520]
    float* a3 = a2 + 16 * 520;        // [16][16]

    const int tid = threadIdx.x;
    const int samp0 = blockIdx.x * 16;

    for (int e = tid; e < 16 * 480; e += 512) {
        int b = e / 480, jc = e - b * 480;
        const float* src = dg + (size_t)(samp0 + b) * 1920 + jc * 4;
        float* dst = ds + b * 1928 + jc * 4;
        dst[0] = src[0]; dst[1] = src[1]; dst[2] = src[2]; dst[3] = src[3];
    }
    __syncthreads();

    const int w = tid >> 6, lane = tid & 63;
    const int oA = w * 128 + lane, oB = oA + 64;
    float accA[16], accB[16];
    {
        float bA = (oA < 960) ? bf1[oA] : 0.0f;
        float bB = (oB < 960) ? bf1[oB] : 0.0f;
        #pragma unroll
        for (int r = 0; r < 16; ++r) { accA[r] = bA; accB[r] = bB; }
    }
    #pragma unroll 2
    for (int kc = 0; kc < 480; ++kc) {
        float4 wA = WT1[kc * 1024 + oA];
        float4 wB = WT1[kc * 1024 + oB];
        #pragma unroll
        for (int r = 0; r < 16; ++r) {
            float4 d4 = ((const float4*)(ds + r * 1928))[kc];
            accA[r] += d4.x * wA.x + d4.y * wA.y + d4.z * wA.z + d4.w * wA.w;
            accB[r] += d4.x * wB.x + d4.y * wB.y + d4.z * wB.z + d4.w * wB.w;
        }
    }
    __syncthreads();
    #pragma unroll
    for (int r = 0; r < 16; ++r) {
        a1[r * 1032 + oA] = fmaxf(accA[r], 0.0f);
        a1[r * 1032 + oB] = fmaxf(accB[r], 0.0f);
    }
    __syncthreads();

    const int o2 = tid;
    float acc2[16];
    {
        float b = (o2 < 480) ? bf2[o2] : 0.0f;
        #pragma unroll
        for (int r = 0; r < 16; ++r) acc2[r] = b;
    }
    #pragma unroll 2
    for (int kc = 0; kc < 256; ++kc) {
        float4 w4 = WT2[kc * 512 + o2];
        #pragma unroll
        for (int r = 0; r < 16; ++r) {
            float4 a4 = ((const float4*)(a1 + r * 1032))[kc];
            acc2[r] += a4.x * w4.x + a4.y * w4.y + a4.z * w4.z + a4.w * w4.w;
        }
    }
    #pragma unroll
    for (int r = 0; r < 16; ++r) a2[r * 520 + o2] = fmaxf(acc2[r], 0.0f);
    __syncthreads();

    if (tid < 256) {
        int o = tid & 15, r = tid >> 4;
        float acc = bf3[o];
        const float4* wr = (const float4*)(Wf3 + (size_t)o * 480);
        const float4* av = (const float4*)(a2 + r * 520);
        #pragma unroll 4
        for (int kc = 0; kc < 120; ++kc) {
            float4 a4 = av[kc];
            float4 w4 = wr[kc];
            acc += a4.x * w4.x + a4.y * w4.y + a4.z * w4.z + a4.w * w4.w;
        }
        a3[r * 16 + o] = fmaxf(acc, 0.0f);
    }
    __syncthreads();

    if (tid < 16) {
        float acc = bf4[0];
        #pragma unroll
        for (int k = 0; k < 16; ++k) acc += a3[tid * 16 + k] * Wf4[k];
        out[samp0 + tid] = acc;
    }
}

extern "C" void kernel_launch(void* const* d_in, const int* in_sizes, int n_in,
                              void* d_out, int out_size, void* d_ws, size_t ws_size,
                              hipStream_t stream) {
    const float* x1   = (const float*)d_in[0];
    const float* x2   = (const float*)d_in[1];
    const float* Wih1 = (const float*)d_in[2];
    const float* Whh1 = (const float*)d_in[3];
    const float* b1   = (const float*)d_in[4];
    const float* Wih2 = (const float*)d_in[5];
    const float* Whh2 = (const float*)d_in[6];
    const float* b2   = (const float*)d_in[7];
    const float* Wih3 = (const float*)d_in[8];
    const float* Whh3 = (const float*)d_in[9];
    const float* b3   = (const float*)d_in[10];
    const float* Wf1  = (const float*)d_in[11];
    const float* bf1  = (const float*)d_in[12];
    const float* Wf2  = (const float*)d_in[13];
    const float* bf2  = (const float*)d_in[14];
    const float* Wf3  = (const float*)d_in[15];
    const float* bf3  = (const float*)d_in[16];
    const float* Wf4  = (const float*)d_in[17];
    const float* bf4  = (const float*)d_in[18];

    float* wsf = (float*)d_ws;
    float* dbuf = wsf;                                         // 4096*1920 = 7,864,320 f32
    unsigned short* l1w = (unsigned short*)(wsf + 7864320);    // 36*32768 = 1,179,648 us
    unsigned short* l2w = l1w + 1179648;                       // 20*8*2048 =  327,680 us
    unsigned short* l3w = l2w + 327680;                        //  6*4*2048 =   49,152 us
    float4* WT1 = (float4*)(wsf + 8642560);                    // 480*1024 float4
    float4* WT2 = WT1 + 480 * 1024;                            // 256*512  float4
    float* xT   = wsf + 11132928;                              // 2*4096*30*64 = 15,728,640 f32
    float* out = (float*)d_out;

    const size_t need_bytes = (size_t)(11132928 + 15728640) * 4u;
    const int xtmode = (ws_size >= need_bytes) ? 1 : 0;

    prep_w32s<<<(36 * 32768) / 256, 256, 0, stream>>>(Wih1, Whh1, l1w);
    prep_w16s<<<(20 * 8 * 2048) / 256, 256, 0, stream>>>(Wih2, Whh2, l2w, 128, 512, 512, 128, 8, 20);
    prep_w16s<<<(6 * 4 * 2048) / 256, 256, 0, stream>>>(Wih3, Whh3, l3w, 64, 128, 128, 64, 4, 6);
    pack_wt1<<<(480 * 1024) / 256, 256, 0, stream>>>(Wf1, WT1);
    pack_wt2<<<(256 * 512) / 256, 256, 0, stream>>>(Wf2, WT2);
    if (xtmode) {
        prep_xt<<<8192, 256, 0, stream>>>(x1, x2, xT);
    }

    (void)hipFuncSetAttribute((const void*)lstm3_v8,
                              hipFuncAttributeMaxDynamicSharedMemorySize, 69120);
    lstm3_v8<<<256, 1024, 69120, stream>>>(x1, x2, xT, xtmode,
                                           l1w, l2w, l3w, b1, b2, b3, dbuf);

    (void)hipFuncSetAttribute((const void*)head_v2,
                              hipFuncAttributeMaxDynamicSharedMemorySize, 16 * 1928 * 4);
    head_v2<<<256, 512, 16 * 1928 * 4, stream>>>(dbuf, WT1, bf1, WT2, bf2,
                                                 Wf3, bf3, Wf4, bf4, out);
}